// Round 9
// baseline (443.190 us; speedup 1.0000x reference)
//
#include <hip/hip_runtime.h>
#include <hip/hip_bf16.h>

// ---------- types / helpers ----------
typedef unsigned short u16;
typedef float f32x4 __attribute__((ext_vector_type(4)));
typedef __bf16 bf16x8 __attribute__((ext_vector_type(8)));
typedef unsigned short u16x8 __attribute__((ext_vector_type(8)));
typedef unsigned short u16x4 __attribute__((ext_vector_type(4)));

__device__ __forceinline__ float b2f(u16 u) {
    unsigned v = ((unsigned)u) << 16;
    return __builtin_bit_cast(float, v);
}
__device__ __forceinline__ u16 f2b(float f) {
    unsigned u = __builtin_bit_cast(unsigned, f);
    u += 0x7fffu + ((u >> 16) & 1u);   // RNE
    return (u16)(u >> 16);
}
__device__ __forceinline__ bf16x8 ldfrag(const u16* p) {
    return __builtin_bit_cast(bf16x8, *(const u16x8*)p);
}
__device__ __forceinline__ f32x4 mfma16(bf16x8 a, bf16x8 b, f32x4 c) {
    return __builtin_amdgcn_mfma_f32_16x16x32_bf16(a, b, c, 0, 0, 0);
}
__device__ __forceinline__ void gload_lds16(const u16* g, u16* l) {
    __builtin_amdgcn_global_load_lds(
        (const __attribute__((address_space(1))) unsigned int*)(g),
        (__attribute__((address_space(3))) unsigned int*)(l), 16, 0, 0);
}

// ---------- problem constants ----------
#define T_TOK 8192
#define DM 768
#define NH 12
#define DH 64
#define DMLP 3072
#define SEQ 1024
#define QKV_LD 2304
#define QK_LD 1536

// ---------- ws arena (u16 offsets) ----------
#define OFF_WQKV ((size_t)0)
#define OFF_WO   (OFF_WQKV + (size_t)2304*768)
#define OFF_WIN  (OFF_WO   + (size_t)768*768)
#define OFF_WOUT (OFF_WIN  + (size_t)768*3072)
#define OFF_BQKV (OFF_WOUT + (size_t)3072*768)          // float[2304] = 4608 u16
#define P0       (OFF_BQKV + (size_t)4608)

#define SZ_N    ((size_t)T_TOK*DM)        // 6,291,456
#define SZ_QKV  ((size_t)T_TOK*QKV_LD)    // 18,874,368 (= QK buf + VtG, exactly)
// Path A: resid_mid lives in d_out (fp32). Peak = P0 + nbuf + qkv + z = 77.1 MB
#define A_NBUF   (P0)
#define A_QKV    (P0 + SZ_N)
#define A_Z      (P0 + SZ_N + SZ_QKV)
#define A_N2     (P0)                       // overlays nbuf (dead after QKV GEMM)
#define A_POST   (P0 + SZ_N)                // overlays qkv+z (dead after O-proj)
#define PATHA_BYTES (((size_t)(P0 + SZ_N + SZ_QKV + SZ_N)) * 2)
// Path B: per-batch attention, 2048-row MLP chunks. Peak = 44.0 MB
#define B_Z      (P0)
#define B_QKVB   (P0 + SZ_N)
#define B_NBUF   (B_QKVB + (size_t)SEQ*QKV_LD)
#define B_N2     (P0)                       // overlays z (dead after O-proj)
#define B_POSTC  (P0 + SZ_N)                // overlays qkvb+nbuf (dead after loop)

// ---------- prep: fp32 -> bf16 weight transposes + fp32 bias concat ----------
#define PR0 (2304*768)
#define PR1 (768*768)
#define PR2 (768*3072)
#define PR3 (3072*768)
#define PREP_TOTAL (PR0+PR1+PR2+PR3+2304)

__global__ __launch_bounds__(256) void prep_kernel(
    const float* __restrict__ WQ, const float* __restrict__ WK, const float* __restrict__ WV,
    const float* __restrict__ WO, const float* __restrict__ Win, const float* __restrict__ Wout,
    const float* __restrict__ bQ, const float* __restrict__ bK, const float* __restrict__ bV,
    u16* __restrict__ Wqkv_t, u16* __restrict__ Wo_t, u16* __restrict__ Win_t,
    u16* __restrict__ Wout_t, float* __restrict__ bias_qkv)
{
    int idx = blockIdx.x * 256 + threadIdx.x;
    if (idx < PR0) {
        int r = idx / 768, d = idx % 768;
        int which = r / 768;
        int he = r % 768;
        int h = he >> 6, e = he & 63;
        const float* W = (which == 0) ? WQ : ((which == 1) ? WK : WV);
        Wqkv_t[idx] = f2b(W[h * 49152 + d * 64 + e]);
    } else if (idx < PR0 + PR1) {
        int o = idx - PR0;
        int d = o / 768, he = o % 768;
        Wo_t[o] = f2b(WO[he * 768 + d]);
    } else if (idx < PR0 + PR1 + PR2) {
        int o = idx - PR0 - PR1;
        int m = o / 768, d = o % 768;
        Win_t[o] = f2b(Win[d * 3072 + m]);
    } else if (idx < PR0 + PR1 + PR2 + PR3) {
        int o = idx - PR0 - PR1 - PR2;
        int d = o / 3072, m = o % 3072;
        Wout_t[o] = f2b(Wout[m * 768 + d]);
    } else if (idx < PREP_TOTAL) {
        int j = idx - (PR0 + PR1 + PR2 + PR3);
        bias_qkv[j] = (j < 768) ? bQ[j] : ((j < 1536) ? bK[j - 768] : bV[j - 1536]);
    }
}

// ---------- layernorm (block per token), fp32 in -> bf16 out ----------
__global__ __launch_bounds__(256) void ln_kernel(
    const float* __restrict__ x, const float* __restrict__ w,
    const float* __restrict__ bb, u16* __restrict__ out)
{
    __shared__ float red[4];
    size_t base = (size_t)blockIdx.x * DM;
    int tid = threadIdx.x;
    float v0 = x[base + tid], v1 = x[base + tid + 256], v2 = x[base + tid + 512];
    float s = v0 + v1 + v2;
#pragma unroll
    for (int off = 32; off > 0; off >>= 1) s += __shfl_xor(s, off);
    if ((tid & 63) == 0) red[tid >> 6] = s;
    __syncthreads();
    float mu = (red[0] + red[1] + red[2] + red[3]) * (1.0f / 768.0f);
    v0 -= mu; v1 -= mu; v2 -= mu;
    float q = v0 * v0 + v1 * v1 + v2 * v2;
    __syncthreads();
#pragma unroll
    for (int off = 32; off > 0; off >>= 1) q += __shfl_xor(q, off);
    if ((tid & 63) == 0) red[tid >> 6] = q;
    __syncthreads();
    float var = (red[0] + red[1] + red[2] + red[3]) * (1.0f / 768.0f);
    float sc = rsqrtf(var + 1e-5f);
    out[base + tid]       = f2b(v0 * sc * w[tid]       + bb[tid]);
    out[base + tid + 256] = f2b(v1 * sc * w[tid + 256] + bb[tid + 256]);
    out[base + tid + 512] = f2b(v2 * sc * w[tid + 512] + bb[tid + 512]);
}

// ---------- GEMM: C[M][N] = A[M][K] @ BT[N][K]^T ----------
// PERSISTENT-BLOCK version (R9): grid = exactly-resident block count; each
// block loops tix += gridDim.x over output tiles. Amortizes prologue ramp /
// vmcnt(0) drain / epilogue across tiles, removes dispatch rounds, and next
// tile's staging overlaps previous epilogue stores (vmcnt counting stays safe:
// in-flight stores only make the counted waits stricter). Tile order: m = tix %
// mTiles with grid % mTiles == 0 -> a block keeps the same A-panel (L2 reuse).
// Inner loop: counted-vmcnt depth-3 (R6 config, proven best; depth-4 was -2%).
// Buffer-race note: kiter ∈ {24,96}, both %3==0, so new-tile prologue (buf0/1)
// never touches the buffer read by the old tile's final iteration (buf2).
// T5 setprio(1) wraps the MFMA cluster (concurrent blocks at different phases
// give the CU scheduler something to arbitrate).
// Transposed-C fragments for EPI 0..3 -> u16x4/f32x4 vector epilogues.
// EPI 4 keeps original orientation (V-transpose write prefers row-packing).
// EPI 0: bf16 out = acc + bias
// EPI 1: f32  out = acc + bias + aux[row*N+col]     (resid_mid -> d_out)
// EPI 2: bf16 out = gelu_new(acc + bias)            (exp-form)
// EPI 3: f32  out = acc + bias + aux[row*N+col]     (final)
// EPI 4: QKV split: cols<1536 -> bf16 out[row*1536+col];
//        cols>=1536 (V) -> transposed VtG[(b*NH+h)*64*1024 + e*1024 + s]
template <int EPI, int TM>
__global__ __launch_bounds__(256) void gemm_bt_kernel(
    const u16* __restrict__ A, const u16* __restrict__ BT,
    const float* __restrict__ bias, const float* __restrict__ aux,
    void* __restrict__ outp, int M, int N, int K)
{
    constexpr int DEPTH = 3;
    __shared__ __align__(16) u16 As[DEPTH][TM * 32];
    __shared__ __align__(16) u16 Bs[DEPTH][128 * 32];
    const int tid = threadIdx.x;
    const int w = tid >> 6, l = tid & 63;
    const int lr = l & 15, lq = l >> 4;
    constexpr int MT = TM / 32;                 // m-frags per wave (4 or 2)
    constexpr bool TR = (EPI != 4);             // transposed-C fragments
    const int wm = (w >> 1) * (TM / 2), wn = (w & 1) * 64;

    const int srow_a = (TM == 128) ? (w * 32 + (l >> 2)) : (w * 16 + (l >> 2));
    const int srow_b = w * 32 + (l >> 2);
    const int scol = (l & 3) * 8;
    const int asd = (TM == 128) ? w * 1024 : w * 512;
    const int bsd = w * 1024;

    const int mTiles = M / TM;
    const int tiles = mTiles * (N >> 7);
    const int kiter = K >> 5;                   // 24 or 96 (both %3 == 0)

#define STAGE_T(kk, s)                                                      \
    {   const int k0_ = (kk) * 32;                                          \
        gload_lds16(Ab + k0_, &As[s][asd]);                                 \
        if constexpr (TM == 128) gload_lds16(Ab + 16 * K + k0_, &As[s][asd + 512]); \
        gload_lds16(Bb + k0_,          &Bs[s][bsd]);                        \
        gload_lds16(Bb + 16 * K + k0_, &Bs[s][bsd + 512]);  }

    for (int tix = blockIdx.x; tix < tiles; tix += gridDim.x) {
        const int bm = (tix % mTiles) * TM;
        const int bn = (tix / mTiles) * 128;
        const u16* Ab = A  + (size_t)(bm + srow_a) * K + scol;
        const u16* Bb = BT + (size_t)(bn + srow_b) * K + scol;

        f32x4 acc[MT][4];
#pragma unroll
        for (int i = 0; i < MT; i++)
#pragma unroll
            for (int j = 0; j < 4; j++) acc[i][j] = f32x4{0.f, 0.f, 0.f, 0.f};

        // prologue: stage tiles 0 and 1 (overlaps previous tile's epilogue stores)
        STAGE_T(0, 0);
        STAGE_T(1, 1);

        int cur = 0;
        for (int t = 0; t < kiter; ++t) {
            // wait: tile t's loads complete; tile t+1's stay in flight
            if (t + 1 < kiter) {
                if constexpr (TM == 128) asm volatile("s_waitcnt vmcnt(4)" ::: "memory");
                else                     asm volatile("s_waitcnt vmcnt(3)" ::: "memory");
            } else {
                asm volatile("s_waitcnt vmcnt(0)" ::: "memory");
            }
            __builtin_amdgcn_s_barrier();
            __builtin_amdgcn_sched_barrier(0);  // pin: nothing moves across sync point

            const u16* Asc = &As[cur][0];
            const u16* Bsc = &Bs[cur][0];
            bf16x8 af[MT], bf[4];
#pragma unroll
            for (int mt = 0; mt < MT; mt++) af[mt] = ldfrag(&Asc[(wm + mt * 16 + lr) * 32 + lq * 8]);
#pragma unroll
            for (int nt = 0; nt < 4; nt++) bf[nt] = ldfrag(&Bsc[(wn + nt * 16 + lr) * 32 + lq * 8]);
            __builtin_amdgcn_s_setprio(1);
#pragma unroll
            for (int mt = 0; mt < MT; mt++)
#pragma unroll
                for (int nt = 0; nt < 4; nt++)
                    acc[mt][nt] = TR ? mfma16(bf[nt], af[mt], acc[mt][nt])
                                     : mfma16(af[mt], bf[nt], acc[mt][nt]);
            __builtin_amdgcn_s_setprio(0);

            if (t + 2 < kiter) {                // stage t+2 into buffer freed at t-1
                int nb = cur + 2; if (nb >= 3) nb -= 3;
                STAGE_T(t + 2, nb);
            }
            cur = (cur + 1 == 3) ? 0 : cur + 1;
        }

        if (EPI == 4) {
            // original orientation: acc[mt][nt][r] = C[row=lq*4+r][col=lr]
            const bool isv = (bn >= 1536);
            u16* vtg = (u16*)aux;             // VtG base (u16), passed via aux
#pragma unroll
            for (int mt = 0; mt < MT; mt++) {
                int row0 = bm + wm + mt * 16 + lq * 4;
                if (!isv) {
#pragma unroll
                    for (int r = 0; r < 4; r++) {
                        size_t ro = (size_t)(row0 + r) * QK_LD;
#pragma unroll
                        for (int nt = 0; nt < 4; nt++) {
                            int col = bn + wn + nt * 16 + lr;
                            ((u16*)outp)[ro + col] = f2b(acc[mt][nt][r] + bias[col]);
                        }
                    }
                } else {
                    int bloc = row0 >> 10;          // batch within this buffer
                    int s = row0 & 1023;            // seq position (multiple of 4)
#pragma unroll
                    for (int nt = 0; nt < 4; nt++) {
                        int col = bn + wn + nt * 16 + lr;
                        int he = col - 1536;        // h*64 + e
                        float bcol = bias[col];
                        u16x4 pk;
                        pk[0] = f2b(acc[mt][nt][0] + bcol);
                        pk[1] = f2b(acc[mt][nt][1] + bcol);
                        pk[2] = f2b(acc[mt][nt][2] + bcol);
                        pk[3] = f2b(acc[mt][nt][3] + bcol);
                        *(u16x4*)&vtg[(size_t)bloc * (NH * 64 * SEQ)
                                      + (size_t)he * SEQ + s] = pk;
                    }
                }
            }
        } else {
            // transposed-C epilogue: thread holds row = wm+mt*16+lr,
            // cols = wn+nt*16+lq*4 .. +3 -> fully vectorized stores.
#pragma unroll
            for (int mt = 0; mt < MT; mt++) {
                int row = bm + wm + mt * 16 + lr;
                size_t ro = (size_t)row * N;
#pragma unroll
                for (int nt = 0; nt < 4; nt++) {
                    int col0 = bn + wn + nt * 16 + lq * 4;
                    f32x4 v = acc[mt][nt] + *(const f32x4*)&bias[col0];
                    if (EPI == 0) {
                        u16x4 pk;
#pragma unroll
                        for (int r = 0; r < 4; r++) pk[r] = f2b(v[r]);
                        *(u16x4*)&((u16*)outp)[ro + col0] = pk;
                    } else if (EPI == 2) {
                        u16x4 pk;
#pragma unroll
                        for (int r = 0; r < 4; r++) {
                            float x = v[r];
                            float y = 0.7978845608028654f * (x + 0.044715f * x * x * x);
                            pk[r] = f2b(x / (1.0f + __expf(-2.0f * y)));
                        }
                        *(u16x4*)&((u16*)outp)[ro + col0] = pk;
                    } else {  // EPI 1 / 3: fp32 out = v + aux
                        f32x4 a4 = *(const f32x4*)&aux[ro + col0];
                        v += a4;
                        *(f32x4*)&((float*)outp)[ro + col0] = v;
                    }
                }
            }
        }
    }
#undef STAGE_T
}

// ---------- flash attention (MFMA): block = (64 q-rows, batch*head) ----------
// Reg-prefetch global->LDS staging for K and Vt + swapped QK^T (lane owns one
// q-row; lane-local softmax, 2 shfls per reduce) + Q in registers.
// LDS 27648 B -> 5 blocks/CU. qk: [token][1536]; vtg: [b][h][e=64][seq=1024].
__global__ __launch_bounds__(256, 5) void attn_kernel(
    const u16* __restrict__ qk, const u16* __restrict__ vtg,
    u16* __restrict__ z, int b0, int bq0)
{
    __shared__ __align__(16) u16 Ks[64 * 72];
    __shared__ __align__(16) u16 Vt[64 * 72];
    __shared__ __align__(16) u16 Ps[4][16 * 72];

    const int qt = (int)(gridDim.x - 1) - (int)blockIdx.x;   // heavy blocks first
    const int bh = blockIdx.y;
    const int b = b0 + bh / NH, h = bh % NH;
    const int tid = threadIdx.x, w = tid >> 6, l = tid & 63;
    const int lr = l & 15, lq = l >> 4;
    const int qbase = qt * 64;
    const u16* qp = qk + (size_t)(b - bq0) * SEQ * QK_LD + h * 64;
    const u16* kp = qp + 768;
    const u16* vthead = vtg + ((size_t)(b - bq0) * NH + h) * (64 * SEQ);
    u16* PsW = &Ps[w][0];

    // Q fragments in registers (B-operand of swapped QK): row w*16+lr, k-slice lq*8
    bf16x8 aq0, aq1;
    {
        const u16* qrow = qp + (size_t)(qbase + w * 16 + lr) * QK_LD + lq * 8;
        aq0 = ldfrag(qrow);
        aq1 = ldfrag(qrow + 32);
    }

    float m_i = -1e30f;       // running max for q = w*16 + lr (softmax domain)
    float l_i = 0.f;          // running denom for q = w*16 + lr
    f32x4 O[4];
#pragma unroll
    for (int i = 0; i < 4; i++) O[i] = f32x4{0.f, 0.f, 0.f, 0.f};

    const int nkt = qt + 1;                 // causal: tiles 0..qt
    const int srow = tid >> 2;              // 0..63  (K row / V e-row)
    const int spart = (tid & 3) * 16;       // 0,16,32,48

    // prefetch tile 0 into registers (T14: issue-early / write-late)
    u16x8 kreg0, kreg1, vreg0, vreg1;
    {
        const u16* ks = kp + (size_t)srow * QK_LD + spart;
        kreg0 = *(const u16x8*)ks;
        kreg1 = *(const u16x8*)(ks + 8);
        const u16* vs = vthead + (size_t)srow * SEQ + spart;
        vreg0 = *(const u16x8*)vs;
        vreg1 = *(const u16x8*)(vs + 8);
    }

    for (int kt = 0; kt < nkt; ++kt) {
        __syncthreads();                    // prev tile's MFMAs done reading Ks/Vt
        *(u16x8*)&Ks[srow * 72 + spart]     = kreg0;
        *(u16x8*)&Ks[srow * 72 + spart + 8] = kreg1;
        *(u16x8*)&Vt[srow * 72 + spart]     = vreg0;
        *(u16x8*)&Vt[srow * 72 + spart + 8] = vreg1;
        __syncthreads();
        if (kt + 1 < nkt) {                 // issue next-tile loads; latency hides under compute
            const u16* ks = kp + (size_t)((kt + 1) * 64 + srow) * QK_LD + spart;
            kreg0 = *(const u16x8*)ks;
            kreg1 = *(const u16x8*)(ks + 8);
            const u16* vs = vthead + (size_t)srow * SEQ + (kt + 1) * 64 + spart;
            vreg0 = *(const u16x8*)vs;
            vreg1 = *(const u16x8*)(vs + 8);
        }

        // ---- swapped QK^T: S^T[k][q], lane holds q = lr, k = nt*16 + lq*4 + r ----
        f32x4 S[4];
#pragma unroll
        for (int nt = 0; nt < 4; nt++) S[nt] = f32x4{0.f, 0.f, 0.f, 0.f};
#pragma unroll
        for (int nt = 0; nt < 4; nt++) {
            bf16x8 bk0 = ldfrag(&Ks[(nt * 16 + lr) * 72 + lq * 8]);
            bf16x8 bk1 = ldfrag(&Ks[(nt * 16 + lr) * 72 + 32 + lq * 8]);
            S[nt] = mfma16(bk0, aq0, S[nt]);
            S[nt] = mfma16(bk1, aq1, S[nt]);
        }

        // ---- online softmax, lane-local per q-row (mask only on diag tile) ----
        const bool diag = (kt == qt);
        float mx = -1e30f;
#pragma unroll
        for (int nt = 0; nt < 4; nt++)
#pragma unroll
            for (int r = 0; r < 4; r++) {
                float sv = S[nt][r] * 0.125f;
                if (diag) sv = (nt * 16 + lq * 4 + r <= w * 16 + lr) ? sv : -1e30f;
                S[nt][r] = sv;
                mx = fmaxf(mx, sv);
            }
        mx = fmaxf(mx, __shfl_xor(mx, 16));
        mx = fmaxf(mx, __shfl_xor(mx, 32));
        float mn = fmaxf(m_i, mx);
        float alpha = __expf(m_i - mn);
        m_i = mn;
        float rs = 0.f;
#pragma unroll
        for (int nt = 0; nt < 4; nt++) {
            u16x4 pk;
#pragma unroll
            for (int r = 0; r < 4; r++) {
                float pe = __expf(S[nt][r] - mn);
                rs += pe;
                pk[r] = f2b(pe);
            }
            // Ps[q = lr][k = nt*16 + lq*4 .. +3], 8B aligned
            *(u16x4*)&PsW[lr * 72 + nt * 16 + lq * 4] = pk;
        }
        rs += __shfl_xor(rs, 16);
        rs += __shfl_xor(rs, 32);
        l_i = l_i * alpha + rs;

        // ---- rescale O (O-domain: lane holds e = lr, q rows lq*4+r) ----
#pragma unroll
        for (int r = 0; r < 4; r++) {
            float ar = __shfl(alpha, (l & 48) | (lq * 4 + r));
            O[0][r] *= ar; O[1][r] *= ar; O[2][r] *= ar; O[3][r] *= ar;
        }

        // ---- PV (Ps is wave-private: no barrier, only lgkmcnt) ----
#pragma unroll
        for (int kq = 0; kq < 2; kq++) {
            bf16x8 ap = ldfrag(&PsW[lr * 72 + kq * 32 + lq * 8]);
#pragma unroll
            for (int ot = 0; ot < 4; ot++) {
                bf16x8 bv = ldfrag(&Vt[(ot * 16 + lr) * 72 + kq * 32 + lq * 8]);
                O[ot] = mfma16(ap, bv, O[ot]);
            }
        }
    }

    // ---- epilogue: bring l_i to O-domain, divide, store ----
    float li[4];
#pragma unroll
    for (int r = 0; r < 4; r++)
        li[r] = __shfl(l_i, (l & 48) | (lq * 4 + r));
#pragma unroll
    for (int ot = 0; ot < 4; ot++)
#pragma unroll
        for (int r = 0; r < 4; r++) {
            int q = qbase + w * 16 + lq * 4 + r;
            size_t t = (size_t)b * SEQ + q;
            z[t * DM + h * 64 + ot * 16 + lr] = f2b(O[ot][r] / li[r]);
        }
}

// ---------- launch ----------
extern "C" void kernel_launch(void* const* d_in, const int* in_sizes, int n_in,
                              void* d_out, int out_size, void* d_ws, size_t ws_size,
                              hipStream_t stream) {
    const float* resid_pre = (const float*)d_in[0];
    const float* W_Q  = (const float*)d_in[1];
    const float* b_Q  = (const float*)d_in[2];
    const float* W_K  = (const float*)d_in[3];
    const float* b_K  = (const float*)d_in[4];
    const float* W_V  = (const float*)d_in[5];
    const float* b_V  = (const float*)d_in[6];
    const float* W_O  = (const float*)d_in[7];
    const float* b_O  = (const float*)d_in[8];
    const float* ln1w = (const float*)d_in[9];
    const float* ln1b = (const float*)d_in[10];
    const float* ln2w = (const float*)d_in[11];
    const float* ln2b = (const float*)d_in[12];
    const float* W_in  = (const float*)d_in[13];
    const float* b_in  = (const float*)d_in[14];
    const float* W_out = (const float*)d_in[15];
    const float* b_out = (const float*)d_in[16];

    u16* ws16       = (u16*)d_ws;
    u16* Wqkv_t     = ws16 + OFF_WQKV;
    u16* Wo_t       = ws16 + OFF_WO;
    u16* Win_t      = ws16 + OFF_WIN;
    u16* Wout_t     = ws16 + OFF_WOUT;
    float* bias_qkv = (float*)(ws16 + OFF_BQKV);
    float* outp  = (float*)d_out;    // fp32 output (reference dtype)
    float* resid = (float*)d_out;    // resid_mid lives in d_out until final add

    prep_kernel<<<(PREP_TOTAL + 255) / 256, 256, 0, stream>>>(
        W_Q, W_K, W_V, W_O, W_in, W_out, b_Q, b_K, b_V,
        Wqkv_t, Wo_t, Win_t, Wout_t, bias_qkv);

    if (ws_size >= PATHA_BYTES) {
        // ---- Path A (77 MB ws) ----
        u16* nbuf    = ws16 + A_NBUF;
        u16* qkbuf   = ws16 + A_QKV;                          // [8192][1536] bf16
        u16* vtgA    = ws16 + A_QKV + (size_t)T_TOK * QK_LD;  // [8][12][64][1024] bf16
        u16* zbuf    = ws16 + A_Z;
        u16* n2buf   = ws16 + A_N2;
        u16* postbuf = ws16 + A_POST;

        ln_kernel<<<T_TOK, 256, 0, stream>>>(resid_pre, ln1w, ln1b, nbuf);
        // QKV: tiles = 64*18 = 1152; grid 576 (mult of mTiles=64) -> 2 tiles/block
        gemm_bt_kernel<4, 128><<<576, 256, 0, stream>>>(
            nbuf, Wqkv_t, bias_qkv, (const float*)vtgA, qkbuf, T_TOK, QKV_LD, DM);
        attn_kernel<<<dim3(SEQ / 64, 8 * NH), 256, 0, stream>>>(qkbuf, vtgA, zbuf, 0, 0);
        // O-proj: tiles = 128*6 = 768; grid 768 -> 1 tile/block (3 blocks/CU)
        gemm_bt_kernel<1, 64><<<768, 256, 0, stream>>>(
            zbuf, Wo_t, b_O, resid_pre, resid, T_TOK, DM, DM);
        ln_kernel<<<T_TOK, 256, 0, stream>>>(resid, ln2w, ln2b, n2buf);
        // MLP-in: tiles = 64*24 = 1536; grid 768 (mult of 64) -> 2 tiles/block
        gemm_bt_kernel<2, 128><<<768, 256, 0, stream>>>(
            n2buf, Win_t, b_in, nullptr, postbuf, T_TOK, DMLP, DM);
        // MLP-out: tiles = 128*6 = 768; grid 768 -> 1 tile/block
        gemm_bt_kernel<3, 64><<<768, 256, 0, stream>>>(
            postbuf, Wout_t, b_out, resid, outp, T_TOK, DM, DMLP);
    } else {
        // ---- Path B (44 MB ws): per-batch attention, chunked MLP ----
        u16* zbuf   = ws16 + B_Z;
        u16* qkb    = ws16 + B_QKVB;                          // [1024][1536] bf16
        u16* vtgB   = qkb + (size_t)SEQ * QK_LD;              // [12][64][1024] bf16
        u16* nbuf   = ws16 + B_NBUF;
        u16* n2buf  = ws16 + B_N2;
        u16* postc  = ws16 + B_POSTC;

        ln_kernel<<<T_TOK, 256, 0, stream>>>(resid_pre, ln1w, ln1b, nbuf);
        for (int b = 0; b < 8; b++) {
            // tiles = 8*18 = 144; grid 144 -> 1 tile/block
            gemm_bt_kernel<4, 128><<<144, 256, 0, stream>>>(
                nbuf + (size_t)b * SEQ * DM, Wqkv_t, bias_qkv, (const float*)vtgB,
                qkb, SEQ, QKV_LD, DM);
            attn_kernel<<<dim3(SEQ / 64, NH), 256, 0, stream>>>(qkb, vtgB, zbuf, b, b);
        }
        gemm_bt_kernel<1, 64><<<768, 256, 0, stream>>>(
            zbuf, Wo_t, b_O, resid_pre, resid, T_TOK, DM, DM);
        ln_kernel<<<T_TOK, 256, 0, stream>>>(resid, ln2w, ln2b, n2buf);
        for (int c = 0; c < 4; c++) {
            const size_t r0 = (size_t)c * 2048;
            // tiles = 16*24 = 384; grid 384 -> 1 tile/block
            gemm_bt_kernel<2, 128><<<384, 256, 0, stream>>>(
                n2buf + r0 * DM, Win_t, b_in, nullptr, postc, 2048, DMLP, DM);
            // tiles = 32*6 = 192; grid 192 -> 1 tile/block
            gemm_bt_kernel<3, 64><<<192, 256, 0, stream>>>(
                postc, Wout_t, b_out, resid + r0 * DM, outp + r0 * DM, 2048, DM, DMLP);
        }
    }
}

// Round 10
// 413.544 us; speedup vs baseline: 1.0717x; 1.0717x over previous
//
#include <hip/hip_runtime.h>
#include <hip/hip_bf16.h>

// ---------- types / helpers ----------
typedef unsigned short u16;
typedef float f32x4 __attribute__((ext_vector_type(4)));
typedef __bf16 bf16x8 __attribute__((ext_vector_type(8)));
typedef unsigned short u16x8 __attribute__((ext_vector_type(8)));
typedef unsigned short u16x4 __attribute__((ext_vector_type(4)));

__device__ __forceinline__ float b2f(u16 u) {
    unsigned v = ((unsigned)u) << 16;
    return __builtin_bit_cast(float, v);
}
__device__ __forceinline__ u16 f2b(float f) {
    unsigned u = __builtin_bit_cast(unsigned, f);
    u += 0x7fffu + ((u >> 16) & 1u);   // RNE
    return (u16)(u >> 16);
}
__device__ __forceinline__ bf16x8 ldfrag(const u16* p) {
    return __builtin_bit_cast(bf16x8, *(const u16x8*)p);
}
__device__ __forceinline__ f32x4 mfma16(bf16x8 a, bf16x8 b, f32x4 c) {
    return __builtin_amdgcn_mfma_f32_16x16x32_bf16(a, b, c, 0, 0, 0);
}
__device__ __forceinline__ void gload_lds16(const u16* g, u16* l) {
    __builtin_amdgcn_global_load_lds(
        (const __attribute__((address_space(1))) unsigned int*)(g),
        (__attribute__((address_space(3))) unsigned int*)(l), 16, 0, 0);
}

// ---------- problem constants ----------
#define T_TOK 8192
#define DM 768
#define NH 12
#define DH 64
#define DMLP 3072
#define SEQ 1024
#define QKV_LD 2304
#define QK_LD 1536

// ---------- ws arena (u16 offsets) ----------
#define OFF_WQKV ((size_t)0)
#define OFF_WO   (OFF_WQKV + (size_t)2304*768)
#define OFF_WIN  (OFF_WO   + (size_t)768*768)
#define OFF_WOUT (OFF_WIN  + (size_t)768*3072)
#define OFF_BQKV (OFF_WOUT + (size_t)3072*768)          // float[2304] = 4608 u16
#define P0       (OFF_BQKV + (size_t)4608)

#define SZ_N    ((size_t)T_TOK*DM)        // 6,291,456
#define SZ_QKV  ((size_t)T_TOK*QKV_LD)    // 18,874,368 (= QK buf + VtG, exactly)
// Path A: resid_mid lives in d_out (fp32). Peak = P0 + nbuf + qkv + z = 77.1 MB
#define A_NBUF   (P0)
#define A_QKV    (P0 + SZ_N)
#define A_Z      (P0 + SZ_N + SZ_QKV)
#define A_N2     (P0)                       // overlays nbuf (dead after QKV GEMM)
#define A_POST   (P0 + SZ_N)                // overlays qkv+z (dead after O-proj)
#define PATHA_BYTES (((size_t)(P0 + SZ_N + SZ_QKV + SZ_N)) * 2)
// Path B: per-batch attention, 2048-row MLP chunks. Peak = 44.0 MB
#define B_Z      (P0)
#define B_QKVB   (P0 + SZ_N)
#define B_NBUF   (B_QKVB + (size_t)SEQ*QKV_LD)
#define B_N2     (P0)                       // overlays z (dead after O-proj)
#define B_POSTC  (P0 + SZ_N)                // overlays qkvb+nbuf (dead after loop)

// ---------- prep: tiled-LDS weight transposes (coalesced) + bias concat ----
// Old prep read fp32 at stride 256B (4x overfetch). New: 64x64 tiles,
// coalesced 64B fp32 reads -> bf16 LDS (transposed store) -> coalesced
// 32B bf16 writes. Tile map (verified vs old index math element-wise):
//  [0,432):    Wqkv  36 (which,h) x 12 d-tiles; in W_sel[h*49152+(d)*64+e]
//  [432,576):  Wo    12x12;  in WO[he*768+d]        -> Wo_t[d*768+he]
//  [576,1152): Win   12(d)x48(m); in Win[d*3072+m]  -> Win_t[m*768+d]
//  [1152,1728):Wout  48(m)x12(d); in Wout[m*768+d]  -> Wout_t[d*3072+m]
//  block 1728: bias concat
#define TT_QKV  432
#define TT_WO   (TT_QKV + 144)
#define TT_WIN  (TT_WO + 576)
#define TT_WOUT (TT_WIN + 576)              // = 1728

__global__ __launch_bounds__(256) void prep_kernel(
    const float* __restrict__ WQ, const float* __restrict__ WK, const float* __restrict__ WV,
    const float* __restrict__ WO, const float* __restrict__ Win, const float* __restrict__ Wout,
    const float* __restrict__ bQ, const float* __restrict__ bK, const float* __restrict__ bV,
    u16* __restrict__ Wqkv_t, u16* __restrict__ Wo_t, u16* __restrict__ Win_t,
    u16* __restrict__ Wout_t, float* __restrict__ bias_qkv)
{
    const int bid = blockIdx.x;
    const int tid = threadIdx.x;
    if (bid == TT_WOUT) {                   // bias concat
        for (int j = tid; j < 2304; j += 256)
            bias_qkv[j] = (j < 768) ? bQ[j] : ((j < 1536) ? bK[j - 768] : bV[j - 1536]);
        return;
    }
    __shared__ u16 tile[64][72];            // [out-row][out-col], pad 72

    const float* sp; u16* dp;
    int sldc, dldc;
    if (bid < TT_QKV) {
        int wh = bid / 12, td = bid % 12;
        int which = wh / 12, h = wh % 12;
        const float* W = (which == 0) ? WQ : ((which == 1) ? WK : WV);
        sp = W + (size_t)h * 49152 + (size_t)(td * 64) * 64;   sldc = 64;
        dp = Wqkv_t + (size_t)(which * 768 + h * 64) * 768 + td * 64; dldc = 768;
    } else if (bid < TT_WO) {
        int t2 = bid - TT_QKV, ti = t2 / 12, tj = t2 % 12;
        sp = WO + (size_t)(ti * 64) * 768 + tj * 64;           sldc = 768;
        dp = Wo_t + (size_t)(tj * 64) * 768 + ti * 64;         dldc = 768;
    } else if (bid < TT_WIN) {
        int t3 = bid - TT_WO, ti = t3 / 48, tj = t3 % 48;
        sp = Win + (size_t)(ti * 64) * 3072 + tj * 64;         sldc = 3072;
        dp = Win_t + (size_t)(tj * 64) * 768 + ti * 64;        dldc = 768;
    } else {
        int t4 = bid - TT_WIN, ti = t4 / 12, tj = t4 % 12;
        sp = Wout + (size_t)(ti * 64) * 768 + tj * 64;         sldc = 768;
        dp = Wout_t + (size_t)(tj * 64) * 3072 + ti * 64;      dldc = 3072;
    }

    // read: thread covers in-row r = tid>>2, in-cols cseg..cseg+15 (coalesced 64B)
    {
        int r = tid >> 2, cseg = (tid & 3) * 16;
        const float* src = sp + (size_t)r * sldc + cseg;
#pragma unroll
        for (int j = 0; j < 16; j++)
            tile[cseg + j][r] = f2b(src[j]);    // transposed store
    }
    __syncthreads();
    // write: thread covers out-row r2 = tid>>2, out-cols c2seg..+15 (coalesced 32B)
    {
        int r2 = tid >> 2, c2seg = (tid & 3) * 16;
        u16* dst = dp + (size_t)r2 * dldc + c2seg;
        *(u16x8*)dst       = *(const u16x8*)&tile[r2][c2seg];
        *(u16x8*)(dst + 8) = *(const u16x8*)&tile[r2][c2seg + 8];
    }
}

// ---------- layernorm (block per token), fp32 in -> bf16 out ----------
__global__ __launch_bounds__(256) void ln_kernel(
    const float* __restrict__ x, const float* __restrict__ w,
    const float* __restrict__ bb, u16* __restrict__ out)
{
    __shared__ float red[4];
    size_t base = (size_t)blockIdx.x * DM;
    int tid = threadIdx.x;
    float v0 = x[base + tid], v1 = x[base + tid + 256], v2 = x[base + tid + 512];
    float s = v0 + v1 + v2;
#pragma unroll
    for (int off = 32; off > 0; off >>= 1) s += __shfl_xor(s, off);
    if ((tid & 63) == 0) red[tid >> 6] = s;
    __syncthreads();
    float mu = (red[0] + red[1] + red[2] + red[3]) * (1.0f / 768.0f);
    v0 -= mu; v1 -= mu; v2 -= mu;
    float q = v0 * v0 + v1 * v1 + v2 * v2;
    __syncthreads();
#pragma unroll
    for (int off = 32; off > 0; off >>= 1) q += __shfl_xor(q, off);
    if ((tid & 63) == 0) red[tid >> 6] = q;
    __syncthreads();
    float var = (red[0] + red[1] + red[2] + red[3]) * (1.0f / 768.0f);
    float sc = rsqrtf(var + 1e-5f);
    out[base + tid]       = f2b(v0 * sc * w[tid]       + bb[tid]);
    out[base + tid + 256] = f2b(v1 * sc * w[tid + 256] + bb[tid + 256]);
    out[base + tid + 512] = f2b(v2 * sc * w[tid + 512] + bb[tid + 512]);
}

// ---------- GEMM: C[M][N] = A[M][K] @ BT[N][K]^T ----------
// EXACT R6 config (proven best: EPI-2 73 us). Counted-vmcnt 3-buf pipeline:
// stage tile t+2 after compute of t; per-iter sync = s_waitcnt vmcnt(LPT) +
// raw s_barrier + sched_barrier(0). Depth-4 (R8), persistent (R9), 256-wide
// N-tile (R7) all tested and neutral-to-worse — this is the plateau of the
// 2-barrier template; further gains need the 8-phase 512-thread rewrite.
// Transposed-C fragments for EPI 0..3 -> u16x4/f32x4 vector epilogues.
// EPI 4 keeps original orientation (V-transpose write prefers row-packing).
// NOTE: SQ_LDS_BANK_CONFLICT ~4.7M is the global_load_lds wide-write artifact
// (bit-identical across 4 layouts) — not a real read conflict.
template <int EPI, int TM>
__global__ __launch_bounds__(256) void gemm_bt_kernel(
    const u16* __restrict__ A, const u16* __restrict__ BT,
    const float* __restrict__ bias, const float* __restrict__ aux,
    void* __restrict__ outp, int N, int K)
{
    __shared__ __align__(16) u16 As[3][TM * 32];
    __shared__ __align__(16) u16 Bs[3][128 * 32];
    const int tid = threadIdx.x;
    const int w = tid >> 6, l = tid & 63;
    const int lr = l & 15, lq = l >> 4;
    const int bm = blockIdx.x * TM, bn = blockIdx.y * 128;
    constexpr int MT = TM / 32;                 // m-frags per wave (4 or 2)
    constexpr bool TR = (EPI != 4);             // transposed-C fragments
    const int wm = (w >> 1) * (TM / 2), wn = (w & 1) * 64;

    f32x4 acc[MT][4];
#pragma unroll
    for (int i = 0; i < MT; i++)
#pragma unroll
        for (int j = 0; j < 4; j++) acc[i][j] = f32x4{0.f, 0.f, 0.f, 0.f};

    const int srow_a = (TM == 128) ? (w * 32 + (l >> 2)) : (w * 16 + (l >> 2));
    const int srow_b = w * 32 + (l >> 2);
    const int scol = (l & 3) * 8;
    const u16* Ab = A  + (size_t)(bm + srow_a) * K + scol;
    const u16* Bb = BT + (size_t)(bn + srow_b) * K + scol;
    const int asd = (TM == 128) ? w * 1024 : w * 512;
    const int bsd = w * 1024;

    const int kiter = K >> 5;                   // >= 24 for all our shapes

#define STAGE_T(kk, s)                                                      \
    {   const int k0_ = (kk) * 32;                                          \
        gload_lds16(Ab + k0_, &As[s][asd]);                                 \
        if constexpr (TM == 128) gload_lds16(Ab + 16 * K + k0_, &As[s][asd + 512]); \
        gload_lds16(Bb + k0_,          &Bs[s][bsd]);                        \
        gload_lds16(Bb + 16 * K + k0_, &Bs[s][bsd + 512]);  }

    // prologue: stage tiles 0 and 1 (depth-2 ahead)
    STAGE_T(0, 0);
    STAGE_T(1, 1);

    int cur = 0;
    for (int t = 0; t < kiter; ++t) {
        // wait: tile t's loads complete; tile t+1's (newest LPT) may stay in flight
        if (t + 1 < kiter) {
            if constexpr (TM == 128) asm volatile("s_waitcnt vmcnt(4)" ::: "memory");
            else                     asm volatile("s_waitcnt vmcnt(3)" ::: "memory");
        } else {
            asm volatile("s_waitcnt vmcnt(0)" ::: "memory");
        }
        __builtin_amdgcn_s_barrier();
        __builtin_amdgcn_sched_barrier(0);      // pin: nothing moves across sync point

        const u16* Asc = &As[cur][0];
        const u16* Bsc = &Bs[cur][0];
        bf16x8 af[MT], bf[4];
#pragma unroll
        for (int mt = 0; mt < MT; mt++) af[mt] = ldfrag(&Asc[(wm + mt * 16 + lr) * 32 + lq * 8]);
#pragma unroll
        for (int nt = 0; nt < 4; nt++) bf[nt] = ldfrag(&Bsc[(wn + nt * 16 + lr) * 32 + lq * 8]);
#pragma unroll
        for (int mt = 0; mt < MT; mt++)
#pragma unroll
            for (int nt = 0; nt < 4; nt++)
                acc[mt][nt] = TR ? mfma16(bf[nt], af[mt], acc[mt][nt])
                                 : mfma16(af[mt], bf[nt], acc[mt][nt]);

        if (t + 2 < kiter) {                    // stage t+2 into the buffer freed at t-1
            int nb = cur + 2; if (nb >= 3) nb -= 3;
            STAGE_T(t + 2, nb);
        }
        cur = (cur + 1 == 3) ? 0 : cur + 1;
    }
#undef STAGE_T

    if (EPI == 4) {
        // original orientation: acc[mt][nt][r] = C[row=lq*4+r within mt][col=lr within nt]
        const bool isv = (bn >= 1536);
        u16* vtg = (u16*)aux;             // VtG base (u16), passed via aux
#pragma unroll
        for (int mt = 0; mt < MT; mt++) {
            int row0 = bm + wm + mt * 16 + lq * 4;
            if (!isv) {
#pragma unroll
                for (int r = 0; r < 4; r++) {
                    size_t ro = (size_t)(row0 + r) * QK_LD;
#pragma unroll
                    for (int nt = 0; nt < 4; nt++) {
                        int col = bn + wn + nt * 16 + lr;
                        ((u16*)outp)[ro + col] = f2b(acc[mt][nt][r] + bias[col]);
                    }
                }
            } else {
                int bloc = row0 >> 10;          // batch within this buffer
                int s = row0 & 1023;            // seq position (multiple of 4)
#pragma unroll
                for (int nt = 0; nt < 4; nt++) {
                    int col = bn + wn + nt * 16 + lr;
                    int he = col - 1536;        // h*64 + e
                    float bcol = bias[col];
                    u16x4 pk;
                    pk[0] = f2b(acc[mt][nt][0] + bcol);
                    pk[1] = f2b(acc[mt][nt][1] + bcol);
                    pk[2] = f2b(acc[mt][nt][2] + bcol);
                    pk[3] = f2b(acc[mt][nt][3] + bcol);
                    *(u16x4*)&vtg[(size_t)bloc * (NH * 64 * SEQ)
                                  + (size_t)he * SEQ + s] = pk;
                }
            }
        }
        return;
    }

    // transposed-C epilogue: thread holds row = wm+mt*16+lr,
    // cols = wn+nt*16+lq*4 .. +3  -> fully vectorized stores.
#pragma unroll
    for (int mt = 0; mt < MT; mt++) {
        int row = bm + wm + mt * 16 + lr;
        size_t ro = (size_t)row * N;
#pragma unroll
        for (int nt = 0; nt < 4; nt++) {
            int col0 = bn + wn + nt * 16 + lq * 4;
            f32x4 v = acc[mt][nt] + *(const f32x4*)&bias[col0];
            if (EPI == 0) {
                u16x4 pk;
#pragma unroll
                for (int r = 0; r < 4; r++) pk[r] = f2b(v[r]);
                *(u16x4*)&((u16*)outp)[ro + col0] = pk;
            } else if (EPI == 2) {
                u16x4 pk;
#pragma unroll
                for (int r = 0; r < 4; r++) {
                    float x = v[r];
                    float y = 0.7978845608028654f * (x + 0.044715f * x * x * x);
                    pk[r] = f2b(x / (1.0f + __expf(-2.0f * y)));
                }
                *(u16x4*)&((u16*)outp)[ro + col0] = pk;
            } else {  // EPI 1 / 3: fp32 out = v + aux
                f32x4 a4 = *(const f32x4*)&aux[ro + col0];
                v += a4;
                *(f32x4*)&((float*)outp)[ro + col0] = v;
            }
        }
    }
}

// ---------- flash attention (MFMA): block = (128 q-rows, batch*head) -------
// QBLK=128 dual-group: each wave owns TWO 16-row q-groups (rows w*32+g*16).
// Halves K/V staging + barriers per MFMA and halves K/V global re-reads vs
// QBLK=64. Causal skip: group fully below the k-tile -> wave-uniform skip
// (last k-tile: waves 0,1 idle through compute but still stage).
// Swapped QK^T (lane owns one q-row; lane-local softmax, 2 shfls/reduce),
// Q in registers, reg-prefetch global->LDS for K and Vt.
// LDS 27648 B. qk: [token][1536]; vtg: [b][h][e=64][seq=1024].
__global__ __launch_bounds__(256, 4) void attn_kernel(
    const u16* __restrict__ qk, const u16* __restrict__ vtg,
    u16* __restrict__ z, int b0, int bq0)
{
    __shared__ __align__(16) u16 Ks[64 * 72];
    __shared__ __align__(16) u16 Vt[64 * 72];
    __shared__ __align__(16) u16 Ps[4][16 * 72];

    const int qt = (int)(gridDim.x - 1) - (int)blockIdx.x;   // heavy blocks first
    const int bh = blockIdx.y;
    const int b = b0 + bh / NH, h = bh % NH;
    const int tid = threadIdx.x, w = tid >> 6, l = tid & 63;
    const int lr = l & 15, lq = l >> 4;
    const int qbase = qt * 128;
    const u16* qp = qk + (size_t)(b - bq0) * SEQ * QK_LD + h * 64;
    const u16* kp = qp + 768;
    const u16* vthead = vtg + ((size_t)(b - bq0) * NH + h) * (64 * SEQ);
    u16* PsW = &Ps[w][0];

    // Q fragments (B-operand of swapped QK): group g row = qbase + w*32+g*16+lr
    bf16x8 aq[2][2];
#pragma unroll
    for (int g = 0; g < 2; g++) {
        const u16* qrow = qp + (size_t)(qbase + w * 32 + g * 16 + lr) * QK_LD + lq * 8;
        aq[g][0] = ldfrag(qrow);
        aq[g][1] = ldfrag(qrow + 32);
    }

    float m_i[2] = {-1e30f, -1e30f};
    float l_i[2] = {0.f, 0.f};
    f32x4 O[2][4];
#pragma unroll
    for (int g = 0; g < 2; g++)
#pragma unroll
        for (int i = 0; i < 4; i++) O[g][i] = f32x4{0.f, 0.f, 0.f, 0.f};

    const int nkt = 2 * qt + 2;             // causal: k-tiles cover [0, qbase+128)
    const int srow = tid >> 2;              // 0..63  (K row / V e-row)
    const int spart = (tid & 3) * 16;       // 0,16,32,48

    // prefetch tile 0 into registers (T14: issue-early / write-late)
    u16x8 kreg0, kreg1, vreg0, vreg1;
    {
        const u16* ks = kp + (size_t)srow * QK_LD + spart;
        kreg0 = *(const u16x8*)ks;
        kreg1 = *(const u16x8*)(ks + 8);
        const u16* vs = vthead + (size_t)srow * SEQ + spart;
        vreg0 = *(const u16x8*)vs;
        vreg1 = *(const u16x8*)(vs + 8);
    }

    for (int kt = 0; kt < nkt; ++kt) {
        __syncthreads();                    // prev tile's MFMAs done reading Ks/Vt
        *(u16x8*)&Ks[srow * 72 + spart]     = kreg0;
        *(u16x8*)&Ks[srow * 72 + spart + 8] = kreg1;
        *(u16x8*)&Vt[srow * 72 + spart]     = vreg0;
        *(u16x8*)&Vt[srow * 72 + spart + 8] = vreg1;
        __syncthreads();
        if (kt + 1 < nkt) {                 // issue next-tile loads; latency hides under compute
            const u16* ks = kp + (size_t)((kt + 1) * 64 + srow) * QK_LD + spart;
            kreg0 = *(const u16x8*)ks;
            kreg1 = *(const u16x8*)(ks + 8);
            const u16* vs = vthead + (size_t)srow * SEQ + (kt + 1) * 64 + spart;
            vreg0 = *(const u16x8*)vs;
            vreg1 = *(const u16x8*)(vs + 8);
        }

        const int krel = kt * 64 - qbase;   // k-tile base relative to qbase

#pragma unroll
        for (int g = 0; g < 2; g++) {
            const int gq0 = w * 32 + g * 16;        // group q-base relative to qbase
            if (krel >= gq0 + 16) continue;         // fully masked (wave-uniform)

            // ---- swapped QK^T: lane holds q = gq0+lr, k = nt*16+lq*4+r ----
            f32x4 S[4];
#pragma unroll
            for (int nt = 0; nt < 4; nt++) S[nt] = f32x4{0.f, 0.f, 0.f, 0.f};
#pragma unroll
            for (int nt = 0; nt < 4; nt++) {
                bf16x8 bk0 = ldfrag(&Ks[(nt * 16 + lr) * 72 + lq * 8]);
                bf16x8 bk1 = ldfrag(&Ks[(nt * 16 + lr) * 72 + 32 + lq * 8]);
                S[nt] = mfma16(bk0, aq[g][0], S[nt]);
                S[nt] = mfma16(bk1, aq[g][1], S[nt]);
            }

            // ---- online softmax, lane-local per q-row ----
            const bool diag = (krel + 63 > gq0);
            float mx = -1e30f;
#pragma unroll
            for (int nt = 0; nt < 4; nt++)
#pragma unroll
                for (int r = 0; r < 4; r++) {
                    float sv = S[nt][r] * 0.125f;
                    if (diag) sv = (krel + nt * 16 + lq * 4 + r <= gq0 + lr) ? sv : -1e30f;
                    S[nt][r] = sv;
                    mx = fmaxf(mx, sv);
                }
            mx = fmaxf(mx, __shfl_xor(mx, 16));
            mx = fmaxf(mx, __shfl_xor(mx, 32));
            float mn = fmaxf(m_i[g], mx);
            float alpha = __expf(m_i[g] - mn);
            m_i[g] = mn;
            float rs = 0.f;
#pragma unroll
            for (int nt = 0; nt < 4; nt++) {
                u16x4 pk;
#pragma unroll
                for (int r = 0; r < 4; r++) {
                    float pe = __expf(S[nt][r] - mn);
                    rs += pe;
                    pk[r] = f2b(pe);
                }
                *(u16x4*)&PsW[lr * 72 + nt * 16 + lq * 4] = pk;
            }
            rs += __shfl_xor(rs, 16);
            rs += __shfl_xor(rs, 32);
            l_i[g] = l_i[g] * alpha + rs;

            // ---- rescale O[g] (O-domain: lane holds e = lr, q rows lq*4+r) ----
#pragma unroll
            for (int r = 0; r < 4; r++) {
                float ar = __shfl(alpha, (l & 48) | (lq * 4 + r));
                O[g][0][r] *= ar; O[g][1][r] *= ar; O[g][2][r] *= ar; O[g][3][r] *= ar;
            }

            // ---- PV (Ps wave-private; compiler orders WAR vs next group) ----
#pragma unroll
            for (int kq = 0; kq < 2; kq++) {
                bf16x8 ap = ldfrag(&PsW[lr * 72 + kq * 32 + lq * 8]);
#pragma unroll
                for (int ot = 0; ot < 4; ot++) {
                    bf16x8 bv = ldfrag(&Vt[(ot * 16 + lr) * 72 + kq * 32 + lq * 8]);
                    O[g][ot] = mfma16(ap, bv, O[g][ot]);
                }
            }
        }
    }

    // ---- epilogue: per group, bring l_i to O-domain, divide, store ----
#pragma unroll
    for (int g = 0; g < 2; g++) {
        float li[4];
#pragma unroll
        for (int r = 0; r < 4; r++)
            li[r] = __shfl(l_i[g], (l & 48) | (lq * 4 + r));
#pragma unroll
        for (int ot = 0; ot < 4; ot++)
#pragma unroll
            for (int r = 0; r < 4; r++) {
                int q = qbase + w * 32 + g * 16 + lq * 4 + r;
                size_t t = (size_t)b * SEQ + q;
                z[t * DM + h * 64 + ot * 16 + lr] = f2b(O[g][ot][r] / li[r]);
            }
    }
}

// ---------- launch ----------
extern "C" void kernel_launch(void* const* d_in, const int* in_sizes, int n_in,
                              void* d_out, int out_size, void* d_ws, size_t ws_size,
                              hipStream_t stream) {
    const float* resid_pre = (const float*)d_in[0];
    const float* W_Q  = (const float*)d_in[1];
    const float* b_Q  = (const float*)d_in[2];
    const float* W_K  = (const float*)d_in[3];
    const float* b_K  = (const float*)d_in[4];
    const float* W_V  = (const float*)d_in[5];
    const float* b_V  = (const float*)d_in[6];
    const float* W_O  = (const float*)d_in[7];
    const float* b_O  = (const float*)d_in[8];
    const float* ln1w = (const float*)d_in[9];
    const float* ln1b = (const float*)d_in[10];
    const float* ln2w = (const float*)d_in[11];
    const float* ln2b = (const float*)d_in[12];
    const float* W_in  = (const float*)d_in[13];
    const float* b_in  = (const float*)d_in[14];
    const float* W_out = (const float*)d_in[15];
    const float* b_out = (const float*)d_in[16];

    u16* ws16       = (u16*)d_ws;
    u16* Wqkv_t     = ws16 + OFF_WQKV;
    u16* Wo_t       = ws16 + OFF_WO;
    u16* Win_t      = ws16 + OFF_WIN;
    u16* Wout_t     = ws16 + OFF_WOUT;
    float* bias_qkv = (float*)(ws16 + OFF_BQKV);
    float* outp  = (float*)d_out;    // fp32 output (reference dtype)
    float* resid = (float*)d_out;    // resid_mid lives in d_out until final add

    prep_kernel<<<TT_WOUT + 1, 256, 0, stream>>>(
        W_Q, W_K, W_V, W_O, W_in, W_out, b_Q, b_K, b_V,
        Wqkv_t, Wo_t, Win_t, Wout_t, bias_qkv);

    if (ws_size >= PATHA_BYTES) {
        // ---- Path A (77 MB ws) ----
        u16* nbuf    = ws16 + A_NBUF;
        u16* qkbuf   = ws16 + A_QKV;                          // [8192][1536] bf16
        u16* vtgA    = ws16 + A_QKV + (size_t)T_TOK * QK_LD;  // [8][12][64][1024] bf16
        u16* zbuf    = ws16 + A_Z;
        u16* n2buf   = ws16 + A_N2;
        u16* postbuf = ws16 + A_POST;

        ln_kernel<<<T_TOK, 256, 0, stream>>>(resid_pre, ln1w, ln1b, nbuf);
        gemm_bt_kernel<4, 128><<<dim3(T_TOK / 128, QKV_LD / 128), 256, 0, stream>>>(
            nbuf, Wqkv_t, bias_qkv, (const float*)vtgA, qkbuf, QKV_LD, DM);
        attn_kernel<<<dim3(SEQ / 128, 8 * NH), 256, 0, stream>>>(qkbuf, vtgA, zbuf, 0, 0);
        gemm_bt_kernel<1, 64><<<dim3(T_TOK / 64, DM / 128), 256, 0, stream>>>(
            zbuf, Wo_t, b_O, resid_pre, resid, DM, DM);
        ln_kernel<<<T_TOK, 256, 0, stream>>>(resid, ln2w, ln2b, n2buf);
        gemm_bt_kernel<2, 128><<<dim3(T_TOK / 128, DMLP / 128), 256, 0, stream>>>(
            n2buf, Win_t, b_in, nullptr, postbuf, DMLP, DM);
        gemm_bt_kernel<3, 64><<<dim3(T_TOK / 64, DM / 128), 256, 0, stream>>>(
            postbuf, Wout_t, b_out, resid, outp, DM, DMLP);
    } else {
        // ---- Path B (44 MB ws): per-batch attention, chunked MLP ----
        u16* zbuf   = ws16 + B_Z;
        u16* qkb    = ws16 + B_QKVB;                          // [1024][1536] bf16
        u16* vtgB   = qkb + (size_t)SEQ * QK_LD;              // [12][64][1024] bf16
        u16* nbuf   = ws16 + B_NBUF;
        u16* n2buf  = ws16 + B_N2;
        u16* postc  = ws16 + B_POSTC;

        ln_kernel<<<T_TOK, 256, 0, stream>>>(resid_pre, ln1w, ln1b, nbuf);
        for (int b = 0; b < 8; b++) {
            gemm_bt_kernel<4, 128><<<dim3(SEQ / 128, QKV_LD / 128), 256, 0, stream>>>(
                nbuf + (size_t)b * SEQ * DM, Wqkv_t, bias_qkv, (const float*)vtgB, qkb, QKV_LD, DM);
            attn_kernel<<<dim3(SEQ / 128, NH), 256, 0, stream>>>(qkb, vtgB, zbuf, b, b);
        }
        gemm_bt_kernel<1, 64><<<dim3(T_TOK / 64, DM / 128), 256, 0, stream>>>(
            zbuf, Wo_t, b_O, resid_pre, resid, DM, DM);
        ln_kernel<<<T_TOK, 256, 0, stream>>>(resid, ln2w, ln2b, n2buf);
        for (int c = 0; c < 4; c++) {
            const size_t r0 = (size_t)c * 2048;
            gemm_bt_kernel<2, 128><<<dim3(2048 / 128, DMLP / 128), 256, 0, stream>>>(
                n2buf + r0 * DM, Win_t, b_in, nullptr, postc, DMLP, DM);
            gemm_bt_kernel<3, 64><<<dim3(2048 / 64, DM / 128), 256, 0, stream>>>(
                postc, Wout_t, b_out, resid + r0 * DM, outp + r0 * DM, DM, DMLP);
        }
    }
}

// Round 11
// 395.773 us; speedup vs baseline: 1.1198x; 1.0449x over previous
//
#include <hip/hip_runtime.h>
#include <hip/hip_bf16.h>

// ---------- types / helpers ----------
typedef unsigned short u16;
typedef float f32x4 __attribute__((ext_vector_type(4)));
typedef __bf16 bf16x8 __attribute__((ext_vector_type(8)));
typedef unsigned short u16x8 __attribute__((ext_vector_type(8)));
typedef unsigned short u16x4 __attribute__((ext_vector_type(4)));

__device__ __forceinline__ float b2f(u16 u) {
    unsigned v = ((unsigned)u) << 16;
    return __builtin_bit_cast(float, v);
}
__device__ __forceinline__ u16 f2b(float f) {
    unsigned u = __builtin_bit_cast(unsigned, f);
    u += 0x7fffu + ((u >> 16) & 1u);   // RNE
    return (u16)(u >> 16);
}
__device__ __forceinline__ bf16x8 ldfrag(const u16* p) {
    return __builtin_bit_cast(bf16x8, *(const u16x8*)p);
}
__device__ __forceinline__ f32x4 mfma16(bf16x8 a, bf16x8 b, f32x4 c) {
    return __builtin_amdgcn_mfma_f32_16x16x32_bf16(a, b, c, 0, 0, 0);
}
__device__ __forceinline__ void gload_lds16(const u16* g, u16* l) {
    __builtin_amdgcn_global_load_lds(
        (const __attribute__((address_space(1))) unsigned int*)(g),
        (__attribute__((address_space(3))) unsigned int*)(l), 16, 0, 0);
}

// ---------- problem constants ----------
#define T_TOK 8192
#define DM 768
#define NH 12
#define DH 64
#define DMLP 3072
#define SEQ 1024
#define QKV_LD 2304
#define QK_LD 1536

// ---------- ws arena (u16 offsets) ----------
#define OFF_WQKV ((size_t)0)
#define OFF_WO   (OFF_WQKV + (size_t)2304*768)
#define OFF_WIN  (OFF_WO   + (size_t)768*768)
#define OFF_WOUT (OFF_WIN  + (size_t)768*3072)
#define OFF_BQKV (OFF_WOUT + (size_t)3072*768)          // float[2304] = 4608 u16
#define P0       (OFF_BQKV + (size_t)4608)

#define SZ_N    ((size_t)T_TOK*DM)        // 6,291,456
#define SZ_QKV  ((size_t)T_TOK*QKV_LD)    // 18,874,368 (= QK buf + VtG, exactly)
// Path A: resid_mid lives in d_out (fp32). Peak = P0 + nbuf + qkv + z = 77.1 MB
#define A_NBUF   (P0)
#define A_QKV    (P0 + SZ_N)
#define A_Z      (P0 + SZ_N + SZ_QKV)
#define A_N2     (P0)                       // overlays nbuf (dead after QKV GEMM)
#define A_POST   (P0 + SZ_N)                // overlays qkv+z (dead after O-proj)
#define PATHA_BYTES (((size_t)(P0 + SZ_N + SZ_QKV + SZ_N)) * 2)
// Path B: per-batch attention, 2048-row MLP chunks. Peak = 44.0 MB
#define B_Z      (P0)
#define B_QKVB   (P0 + SZ_N)
#define B_NBUF   (B_QKVB + (size_t)SEQ*QKV_LD)
#define B_N2     (P0)                       // overlays z (dead after O-proj)
#define B_POSTC  (P0 + SZ_N)                // overlays qkvb+nbuf (dead after loop)

// ---------- prep: tiled-LDS weight transposes (coalesced) + bias concat ----
// R10 version (saved ~30 us vs strided original). 64x64 tiles, coalesced 64B
// fp32 reads -> bf16 LDS (transposed store) -> coalesced 32B bf16 writes.
//  [0,432):    Wqkv  36 (which,h) x 12 d-tiles
//  [432,576):  Wo    12x12
//  [576,1152): Win   12(d)x48(m)
//  [1152,1728):Wout  48(m)x12(d)
//  block 1728: bias concat
#define TT_QKV  432
#define TT_WO   (TT_QKV + 144)
#define TT_WIN  (TT_WO + 576)
#define TT_WOUT (TT_WIN + 576)              // = 1728

__global__ __launch_bounds__(256) void prep_kernel(
    const float* __restrict__ WQ, const float* __restrict__ WK, const float* __restrict__ WV,
    const float* __restrict__ WO, const float* __restrict__ Win, const float* __restrict__ Wout,
    const float* __restrict__ bQ, const float* __restrict__ bK, const float* __restrict__ bV,
    u16* __restrict__ Wqkv_t, u16* __restrict__ Wo_t, u16* __restrict__ Win_t,
    u16* __restrict__ Wout_t, float* __restrict__ bias_qkv)
{
    const int bid = blockIdx.x;
    const int tid = threadIdx.x;
    if (bid == TT_WOUT) {                   // bias concat
        for (int j = tid; j < 2304; j += 256)
            bias_qkv[j] = (j < 768) ? bQ[j] : ((j < 1536) ? bK[j - 768] : bV[j - 1536]);
        return;
    }
    __shared__ u16 tile[64][72];            // [out-row][out-col], pad 72

    const float* sp; u16* dp;
    int sldc, dldc;
    if (bid < TT_QKV) {
        int wh = bid / 12, td = bid % 12;
        int which = wh / 12, h = wh % 12;
        const float* W = (which == 0) ? WQ : ((which == 1) ? WK : WV);
        sp = W + (size_t)h * 49152 + (size_t)(td * 64) * 64;   sldc = 64;
        dp = Wqkv_t + (size_t)(which * 768 + h * 64) * 768 + td * 64; dldc = 768;
    } else if (bid < TT_WO) {
        int t2 = bid - TT_QKV, ti = t2 / 12, tj = t2 % 12;
        sp = WO + (size_t)(ti * 64) * 768 + tj * 64;           sldc = 768;
        dp = Wo_t + (size_t)(tj * 64) * 768 + ti * 64;         dldc = 768;
    } else if (bid < TT_WIN) {
        int t3 = bid - TT_WO, ti = t3 / 48, tj = t3 % 48;
        sp = Win + (size_t)(ti * 64) * 3072 + tj * 64;         sldc = 3072;
        dp = Win_t + (size_t)(tj * 64) * 768 + ti * 64;        dldc = 768;
    } else {
        int t4 = bid - TT_WIN, ti = t4 / 12, tj = t4 % 12;
        sp = Wout + (size_t)(ti * 64) * 768 + tj * 64;         sldc = 768;
        dp = Wout_t + (size_t)(tj * 64) * 3072 + ti * 64;      dldc = 3072;
    }

    // read: thread covers in-row r = tid>>2, in-cols cseg..cseg+15 (coalesced 64B)
    {
        int r = tid >> 2, cseg = (tid & 3) * 16;
        const float* src = sp + (size_t)r * sldc + cseg;
#pragma unroll
        for (int j = 0; j < 16; j++)
            tile[cseg + j][r] = f2b(src[j]);    // transposed store
    }
    __syncthreads();
    // write: thread covers out-row r2 = tid>>2, out-cols c2seg..+15 (coalesced 32B)
    {
        int r2 = tid >> 2, c2seg = (tid & 3) * 16;
        u16* dst = dp + (size_t)r2 * dldc + c2seg;
        *(u16x8*)dst       = *(const u16x8*)&tile[r2][c2seg];
        *(u16x8*)(dst + 8) = *(const u16x8*)&tile[r2][c2seg + 8];
    }
}

// ---------- layernorm (block per token), fp32 in -> bf16 out ----------
__global__ __launch_bounds__(256) void ln_kernel(
    const float* __restrict__ x, const float* __restrict__ w,
    const float* __restrict__ bb, u16* __restrict__ out)
{
    __shared__ float red[4];
    size_t base = (size_t)blockIdx.x * DM;
    int tid = threadIdx.x;
    float v0 = x[base + tid], v1 = x[base + tid + 256], v2 = x[base + tid + 512];
    float s = v0 + v1 + v2;
#pragma unroll
    for (int off = 32; off > 0; off >>= 1) s += __shfl_xor(s, off);
    if ((tid & 63) == 0) red[tid >> 6] = s;
    __syncthreads();
    float mu = (red[0] + red[1] + red[2] + red[3]) * (1.0f / 768.0f);
    v0 -= mu; v1 -= mu; v2 -= mu;
    float q = v0 * v0 + v1 * v1 + v2 * v2;
    __syncthreads();
#pragma unroll
    for (int off = 32; off > 0; off >>= 1) q += __shfl_xor(q, off);
    if ((tid & 63) == 0) red[tid >> 6] = q;
    __syncthreads();
    float var = (red[0] + red[1] + red[2] + red[3]) * (1.0f / 768.0f);
    float sc = rsqrtf(var + 1e-5f);
    out[base + tid]       = f2b(v0 * sc * w[tid]       + bb[tid]);
    out[base + tid + 256] = f2b(v1 * sc * w[tid + 256] + bb[tid + 256]);
    out[base + tid + 512] = f2b(v2 * sc * w[tid + 512] + bb[tid + 512]);
}

// ---------- GEMM: C[M][N] = A[M][K] @ BT[N][K]^T ----------
// EXACT R6 config (proven best: EPI-2 73 us). Counted-vmcnt 3-buf pipeline:
// stage tile t+2 after compute of t; per-iter sync = s_waitcnt vmcnt(LPT) +
// raw s_barrier + sched_barrier(0). Depth-4 (R8), persistent (R9), 256-wide
// N-tile (R7) all tested and neutral-to-worse — this is the plateau of the
// 2-barrier template; further gains need the 8-phase 512-thread rewrite.
// Transposed-C fragments for EPI 0..3 -> u16x4/f32x4 vector epilogues.
// EPI 4 keeps original orientation (V-transpose write prefers row-packing).
// NOTE: SQ_LDS_BANK_CONFLICT ~4.7M is the global_load_lds wide-write artifact
// (bit-identical across 4 layouts) — not a real read conflict.
template <int EPI, int TM>
__global__ __launch_bounds__(256) void gemm_bt_kernel(
    const u16* __restrict__ A, const u16* __restrict__ BT,
    const float* __restrict__ bias, const float* __restrict__ aux,
    void* __restrict__ outp, int N, int K)
{
    __shared__ __align__(16) u16 As[3][TM * 32];
    __shared__ __align__(16) u16 Bs[3][128 * 32];
    const int tid = threadIdx.x;
    const int w = tid >> 6, l = tid & 63;
    const int lr = l & 15, lq = l >> 4;
    const int bm = blockIdx.x * TM, bn = blockIdx.y * 128;
    constexpr int MT = TM / 32;                 // m-frags per wave (4 or 2)
    constexpr bool TR = (EPI != 4);             // transposed-C fragments
    const int wm = (w >> 1) * (TM / 2), wn = (w & 1) * 64;

    f32x4 acc[MT][4];
#pragma unroll
    for (int i = 0; i < MT; i++)
#pragma unroll
        for (int j = 0; j < 4; j++) acc[i][j] = f32x4{0.f, 0.f, 0.f, 0.f};

    const int srow_a = (TM == 128) ? (w * 32 + (l >> 2)) : (w * 16 + (l >> 2));
    const int srow_b = w * 32 + (l >> 2);
    const int scol = (l & 3) * 8;
    const u16* Ab = A  + (size_t)(bm + srow_a) * K + scol;
    const u16* Bb = BT + (size_t)(bn + srow_b) * K + scol;
    const int asd = (TM == 128) ? w * 1024 : w * 512;
    const int bsd = w * 1024;

    const int kiter = K >> 5;                   // >= 24 for all our shapes

#define STAGE_T(kk, s)                                                      \
    {   const int k0_ = (kk) * 32;                                          \
        gload_lds16(Ab + k0_, &As[s][asd]);                                 \
        if constexpr (TM == 128) gload_lds16(Ab + 16 * K + k0_, &As[s][asd + 512]); \
        gload_lds16(Bb + k0_,          &Bs[s][bsd]);                        \
        gload_lds16(Bb + 16 * K + k0_, &Bs[s][bsd + 512]);  }

    // prologue: stage tiles 0 and 1 (depth-2 ahead)
    STAGE_T(0, 0);
    STAGE_T(1, 1);

    int cur = 0;
    for (int t = 0; t < kiter; ++t) {
        // wait: tile t's loads complete; tile t+1's (newest LPT) may stay in flight
        if (t + 1 < kiter) {
            if constexpr (TM == 128) asm volatile("s_waitcnt vmcnt(4)" ::: "memory");
            else                     asm volatile("s_waitcnt vmcnt(3)" ::: "memory");
        } else {
            asm volatile("s_waitcnt vmcnt(0)" ::: "memory");
        }
        __builtin_amdgcn_s_barrier();
        __builtin_amdgcn_sched_barrier(0);      // pin: nothing moves across sync point

        const u16* Asc = &As[cur][0];
        const u16* Bsc = &Bs[cur][0];
        bf16x8 af[MT], bf[4];
#pragma unroll
        for (int mt = 0; mt < MT; mt++) af[mt] = ldfrag(&Asc[(wm + mt * 16 + lr) * 32 + lq * 8]);
#pragma unroll
        for (int nt = 0; nt < 4; nt++) bf[nt] = ldfrag(&Bsc[(wn + nt * 16 + lr) * 32 + lq * 8]);
#pragma unroll
        for (int mt = 0; mt < MT; mt++)
#pragma unroll
            for (int nt = 0; nt < 4; nt++)
                acc[mt][nt] = TR ? mfma16(bf[nt], af[mt], acc[mt][nt])
                                 : mfma16(af[mt], bf[nt], acc[mt][nt]);

        if (t + 2 < kiter) {                    // stage t+2 into the buffer freed at t-1
            int nb = cur + 2; if (nb >= 3) nb -= 3;
            STAGE_T(t + 2, nb);
        }
        cur = (cur + 1 == 3) ? 0 : cur + 1;
    }
#undef STAGE_T

    if (EPI == 4) {
        // original orientation: acc[mt][nt][r] = C[row=lq*4+r within mt][col=lr within nt]
        const bool isv = (bn >= 1536);
        u16* vtg = (u16*)aux;             // VtG base (u16), passed via aux
#pragma unroll
        for (int mt = 0; mt < MT; mt++) {
            int row0 = bm + wm + mt * 16 + lq * 4;
            if (!isv) {
#pragma unroll
                for (int r = 0; r < 4; r++) {
                    size_t ro = (size_t)(row0 + r) * QK_LD;
#pragma unroll
                    for (int nt = 0; nt < 4; nt++) {
                        int col = bn + wn + nt * 16 + lr;
                        ((u16*)outp)[ro + col] = f2b(acc[mt][nt][r] + bias[col]);
                    }
                }
            } else {
                int bloc = row0 >> 10;          // batch within this buffer
                int s = row0 & 1023;            // seq position (multiple of 4)
#pragma unroll
                for (int nt = 0; nt < 4; nt++) {
                    int col = bn + wn + nt * 16 + lr;
                    int he = col - 1536;        // h*64 + e
                    float bcol = bias[col];
                    u16x4 pk;
                    pk[0] = f2b(acc[mt][nt][0] + bcol);
                    pk[1] = f2b(acc[mt][nt][1] + bcol);
                    pk[2] = f2b(acc[mt][nt][2] + bcol);
                    pk[3] = f2b(acc[mt][nt][3] + bcol);
                    *(u16x4*)&vtg[(size_t)bloc * (NH * 64 * SEQ)
                                  + (size_t)he * SEQ + s] = pk;
                }
            }
        }
        return;
    }

    // transposed-C epilogue: thread holds row = wm+mt*16+lr,
    // cols = wn+nt*16+lq*4 .. +3  -> fully vectorized stores.
#pragma unroll
    for (int mt = 0; mt < MT; mt++) {
        int row = bm + wm + mt * 16 + lr;
        size_t ro = (size_t)row * N;
#pragma unroll
        for (int nt = 0; nt < 4; nt++) {
            int col0 = bn + wn + nt * 16 + lq * 4;
            f32x4 v = acc[mt][nt] + *(const f32x4*)&bias[col0];
            if (EPI == 0) {
                u16x4 pk;
#pragma unroll
                for (int r = 0; r < 4; r++) pk[r] = f2b(v[r]);
                *(u16x4*)&((u16*)outp)[ro + col0] = pk;
            } else if (EPI == 2) {
                u16x4 pk;
#pragma unroll
                for (int r = 0; r < 4; r++) {
                    float x = v[r];
                    float y = 0.7978845608028654f * (x + 0.044715f * x * x * x);
                    pk[r] = f2b(x / (1.0f + __expf(-2.0f * y)));
                }
                *(u16x4*)&((u16*)outp)[ro + col0] = pk;
            } else {  // EPI 1 / 3: fp32 out = v + aux
                f32x4 a4 = *(const f32x4*)&aux[ro + col0];
                v += a4;
                *(f32x4*)&((float*)outp)[ro + col0] = v;
            }
        }
    }
}

// ---------- flash attention (MFMA): block = (64 q-rows, batch*head) ----------
// EXACT R6 attention (proven ~65 us). QBLK=128 dual-group (R10) regressed to
// 84 us: halved block count + doubled per-wave serial softmax chain -> longer
// makespan. QBLK=64: reg-prefetch global->LDS staging for K and Vt + swapped
// QK^T (lane owns one q-row; lane-local softmax, 2 shfls per reduce) + Q in
// registers. LDS 27648 B -> 5 blocks/CU. qk: [token][1536]; vtg: [b][h][e][s].
__global__ __launch_bounds__(256, 5) void attn_kernel(
    const u16* __restrict__ qk, const u16* __restrict__ vtg,
    u16* __restrict__ z, int b0, int bq0)
{
    __shared__ __align__(16) u16 Ks[64 * 72];
    __shared__ __align__(16) u16 Vt[64 * 72];
    __shared__ __align__(16) u16 Ps[4][16 * 72];

    const int qt = (int)(gridDim.x - 1) - (int)blockIdx.x;   // heavy blocks first
    const int bh = blockIdx.y;
    const int b = b0 + bh / NH, h = bh % NH;
    const int tid = threadIdx.x, w = tid >> 6, l = tid & 63;
    const int lr = l & 15, lq = l >> 4;
    const int qbase = qt * 64;
    const u16* qp = qk + (size_t)(b - bq0) * SEQ * QK_LD + h * 64;
    const u16* kp = qp + 768;
    const u16* vthead = vtg + ((size_t)(b - bq0) * NH + h) * (64 * SEQ);
    u16* PsW = &Ps[w][0];

    // Q fragments in registers (B-operand of swapped QK): row w*16+lr, k-slice lq*8
    bf16x8 aq0, aq1;
    {
        const u16* qrow = qp + (size_t)(qbase + w * 16 + lr) * QK_LD + lq * 8;
        aq0 = ldfrag(qrow);
        aq1 = ldfrag(qrow + 32);
    }

    float m_i = -1e30f;       // running max for q = w*16 + lr (softmax domain)
    float l_i = 0.f;          // running denom for q = w*16 + lr
    f32x4 O[4];
#pragma unroll
    for (int i = 0; i < 4; i++) O[i] = f32x4{0.f, 0.f, 0.f, 0.f};

    const int nkt = qt + 1;                 // causal: tiles 0..qt
    const int srow = tid >> 2;              // 0..63  (K row / V e-row)
    const int spart = (tid & 3) * 16;       // 0,16,32,48

    // prefetch tile 0 into registers (T14: issue-early / write-late)
    u16x8 kreg0, kreg1, vreg0, vreg1;
    {
        const u16* ks = kp + (size_t)srow * QK_LD + spart;
        kreg0 = *(const u16x8*)ks;
        kreg1 = *(const u16x8*)(ks + 8);
        const u16* vs = vthead + (size_t)srow * SEQ + spart;
        vreg0 = *(const u16x8*)vs;
        vreg1 = *(const u16x8*)(vs + 8);
    }

    for (int kt = 0; kt < nkt; ++kt) {
        __syncthreads();                    // prev tile's MFMAs done reading Ks/Vt
        *(u16x8*)&Ks[srow * 72 + spart]     = kreg0;
        *(u16x8*)&Ks[srow * 72 + spart + 8] = kreg1;
        *(u16x8*)&Vt[srow * 72 + spart]     = vreg0;
        *(u16x8*)&Vt[srow * 72 + spart + 8] = vreg1;
        __syncthreads();
        if (kt + 1 < nkt) {                 // issue next-tile loads; latency hides under compute
            const u16* ks = kp + (size_t)((kt + 1) * 64 + srow) * QK_LD + spart;
            kreg0 = *(const u16x8*)ks;
            kreg1 = *(const u16x8*)(ks + 8);
            const u16* vs = vthead + (size_t)srow * SEQ + (kt + 1) * 64 + spart;
            vreg0 = *(const u16x8*)vs;
            vreg1 = *(const u16x8*)(vs + 8);
        }

        // ---- swapped QK^T: S^T[k][q], lane holds q = lr, k = nt*16 + lq*4 + r ----
        f32x4 S[4];
#pragma unroll
        for (int nt = 0; nt < 4; nt++) S[nt] = f32x4{0.f, 0.f, 0.f, 0.f};
#pragma unroll
        for (int nt = 0; nt < 4; nt++) {
            bf16x8 bk0 = ldfrag(&Ks[(nt * 16 + lr) * 72 + lq * 8]);
            bf16x8 bk1 = ldfrag(&Ks[(nt * 16 + lr) * 72 + 32 + lq * 8]);
            S[nt] = mfma16(bk0, aq0, S[nt]);
            S[nt] = mfma16(bk1, aq1, S[nt]);
        }

        // ---- online softmax, lane-local per q-row (mask only on diag tile) ----
        const bool diag = (kt == qt);
        float mx = -1e30f;
#pragma unroll
        for (int nt = 0; nt < 4; nt++)
#pragma unroll
            for (int r = 0; r < 4; r++) {
                float sv = S[nt][r] * 0.125f;
                if (diag) sv = (nt * 16 + lq * 4 + r <= w * 16 + lr) ? sv : -1e30f;
                S[nt][r] = sv;
                mx = fmaxf(mx, sv);
            }
        mx = fmaxf(mx, __shfl_xor(mx, 16));
        mx = fmaxf(mx, __shfl_xor(mx, 32));
        float mn = fmaxf(m_i, mx);
        float alpha = __expf(m_i - mn);
        m_i = mn;
        float rs = 0.f;
#pragma unroll
        for (int nt = 0; nt < 4; nt++) {
            u16x4 pk;
#pragma unroll
            for (int r = 0; r < 4; r++) {
                float pe = __expf(S[nt][r] - mn);
                rs += pe;
                pk[r] = f2b(pe);
            }
            // Ps[q = lr][k = nt*16 + lq*4 .. +3], 8B aligned
            *(u16x4*)&PsW[lr * 72 + nt * 16 + lq * 4] = pk;
        }
        rs += __shfl_xor(rs, 16);
        rs += __shfl_xor(rs, 32);
        l_i = l_i * alpha + rs;

        // ---- rescale O (O-domain: lane holds e = lr, q rows lq*4+r) ----
#pragma unroll
        for (int r = 0; r < 4; r++) {
            float ar = __shfl(alpha, (l & 48) | (lq * 4 + r));
            O[0][r] *= ar; O[1][r] *= ar; O[2][r] *= ar; O[3][r] *= ar;
        }

        // ---- PV (Ps is wave-private: no barrier, only lgkmcnt) ----
#pragma unroll
        for (int kq = 0; kq < 2; kq++) {
            bf16x8 ap = ldfrag(&PsW[lr * 72 + kq * 32 + lq * 8]);
#pragma unroll
            for (int ot = 0; ot < 4; ot++) {
                bf16x8 bv = ldfrag(&Vt[(ot * 16 + lr) * 72 + kq * 32 + lq * 8]);
                O[ot] = mfma16(ap, bv, O[ot]);
            }
        }
    }

    // ---- epilogue: bring l_i to O-domain, divide, store ----
    float li[4];
#pragma unroll
    for (int r = 0; r < 4; r++)
        li[r] = __shfl(l_i, (l & 48) | (lq * 4 + r));
#pragma unroll
    for (int ot = 0; ot < 4; ot++)
#pragma unroll
        for (int r = 0; r < 4; r++) {
            int q = qbase + w * 16 + lq * 4 + r;
            size_t t = (size_t)b * SEQ + q;
            z[t * DM + h * 64 + ot * 16 + lr] = f2b(O[ot][r] / li[r]);
        }
}

// ---------- launch ----------
extern "C" void kernel_launch(void* const* d_in, const int* in_sizes, int n_in,
                              void* d_out, int out_size, void* d_ws, size_t ws_size,
                              hipStream_t stream) {
    const float* resid_pre = (const float*)d_in[0];
    const float* W_Q  = (const float*)d_in[1];
    const float* b_Q  = (const float*)d_in[2];
    const float* W_K  = (const float*)d_in[3];
    const float* b_K  = (const float*)d_in[4];
    const float* W_V  = (const float*)d_in[5];
    const float* b_V  = (const float*)d_in[6];
    const float* W_O  = (const float*)d_in[7];
    const float* b_O  = (const float*)d_in[8];
    const float* ln1w = (const float*)d_in[9];
    const float* ln1b = (const float*)d_in[10];
    const float* ln2w = (const float*)d_in[11];
    const float* ln2b = (const float*)d_in[12];
    const float* W_in  = (const float*)d_in[13];
    const float* b_in  = (const float*)d_in[14];
    const float* W_out = (const float*)d_in[15];
    const float* b_out = (const float*)d_in[16];

    u16* ws16       = (u16*)d_ws;
    u16* Wqkv_t     = ws16 + OFF_WQKV;
    u16* Wo_t       = ws16 + OFF_WO;
    u16* Win_t      = ws16 + OFF_WIN;
    u16* Wout_t     = ws16 + OFF_WOUT;
    float* bias_qkv = (float*)(ws16 + OFF_BQKV);
    float* outp  = (float*)d_out;    // fp32 output (reference dtype)
    float* resid = (float*)d_out;    // resid_mid lives in d_out until final add

    prep_kernel<<<TT_WOUT + 1, 256, 0, stream>>>(
        W_Q, W_K, W_V, W_O, W_in, W_out, b_Q, b_K, b_V,
        Wqkv_t, Wo_t, Win_t, Wout_t, bias_qkv);

    if (ws_size >= PATHA_BYTES) {
        // ---- Path A (77 MB ws) ----
        u16* nbuf    = ws16 + A_NBUF;
        u16* qkbuf   = ws16 + A_QKV;                          // [8192][1536] bf16
        u16* vtgA    = ws16 + A_QKV + (size_t)T_TOK * QK_LD;  // [8][12][64][1024] bf16
        u16* zbuf    = ws16 + A_Z;
        u16* n2buf   = ws16 + A_N2;
        u16* postbuf = ws16 + A_POST;

        ln_kernel<<<T_TOK, 256, 0, stream>>>(resid_pre, ln1w, ln1b, nbuf);
        gemm_bt_kernel<4, 128><<<dim3(T_TOK / 128, QKV_LD / 128), 256, 0, stream>>>(
            nbuf, Wqkv_t, bias_qkv, (const float*)vtgA, qkbuf, QKV_LD, DM);
        attn_kernel<<<dim3(SEQ / 64, 8 * NH), 256, 0, stream>>>(qkbuf, vtgA, zbuf, 0, 0);
        gemm_bt_kernel<1, 64><<<dim3(T_TOK / 64, DM / 128), 256, 0, stream>>>(
            zbuf, Wo_t, b_O, resid_pre, resid, DM, DM);
        ln_kernel<<<T_TOK, 256, 0, stream>>>(resid, ln2w, ln2b, n2buf);
        gemm_bt_kernel<2, 128><<<dim3(T_TOK / 128, DMLP / 128), 256, 0, stream>>>(
            n2buf, Win_t, b_in, nullptr, postbuf, DMLP, DM);
        gemm_bt_kernel<3, 64><<<dim3(T_TOK / 64, DM / 128), 256, 0, stream>>>(
            postbuf, Wout_t, b_out, resid, outp, DM, DMLP);
    } else {
        // ---- Path B (44 MB ws): per-batch attention, chunked MLP ----
        u16* zbuf   = ws16 + B_Z;
        u16* qkb    = ws16 + B_QKVB;                          // [1024][1536] bf16
        u16* vtgB   = qkb + (size_t)SEQ * QK_LD;              // [12][64][1024] bf16
        u16* nbuf   = ws16 + B_NBUF;
        u16* n2buf  = ws16 + B_N2;
        u16* postc  = ws16 + B_POSTC;

        ln_kernel<<<T_TOK, 256, 0, stream>>>(resid_pre, ln1w, ln1b, nbuf);
        for (int b = 0; b < 8; b++) {
            gemm_bt_kernel<4, 128><<<dim3(SEQ / 128, QKV_LD / 128), 256, 0, stream>>>(
                nbuf + (size_t)b * SEQ * DM, Wqkv_t, bias_qkv, (const float*)vtgB, qkb, QKV_LD, DM);
            attn_kernel<<<dim3(SEQ / 64, NH), 256, 0, stream>>>(qkb, vtgB, zbuf, b, b);
        }
        gemm_bt_kernel<1, 64><<<dim3(T_TOK / 64, DM / 128), 256, 0, stream>>>(
            zbuf, Wo_t, b_O, resid_pre, resid, DM, DM);
        ln_kernel<<<T_TOK, 256, 0, stream>>>(resid, ln2w, ln2b, n2buf);
        for (int c = 0; c < 4; c++) {
            const size_t r0 = (size_t)c * 2048;
            gemm_bt_kernel<2, 128><<<dim3(2048 / 128, DMLP / 128), 256, 0, stream>>>(
                n2buf + r0 * DM, Win_t, b_in, nullptr, postc, DMLP, DM);
            gemm_bt_kernel<3, 64><<<dim3(2048 / 64, DM / 128), 256, 0, stream>>>(
                postc, Wout_t, b_out, resid + r0 * DM, outp + r0 * DM, DM, DMLP);
        }
    }
}

// Round 12
// 381.632 us; speedup vs baseline: 1.1613x; 1.0371x over previous
//
#include <hip/hip_runtime.h>
#include <hip/hip_bf16.h>

// ---------- types / helpers ----------
typedef unsigned short u16;
typedef float f32x4 __attribute__((ext_vector_type(4)));
typedef __bf16 bf16x8 __attribute__((ext_vector_type(8)));
typedef unsigned short u16x8 __attribute__((ext_vector_type(8)));
typedef unsigned short u16x4 __attribute__((ext_vector_type(4)));

__device__ __forceinline__ float b2f(u16 u) {
    unsigned v = ((unsigned)u) << 16;
    return __builtin_bit_cast(float, v);
}
__device__ __forceinline__ u16 f2b(float f) {
    unsigned u = __builtin_bit_cast(unsigned, f);
    u += 0x7fffu + ((u >> 16) & 1u);   // RNE
    return (u16)(u >> 16);
}
__device__ __forceinline__ bf16x8 ldfrag(const u16* p) {
    return __builtin_bit_cast(bf16x8, *(const u16x8*)p);
}
__device__ __forceinline__ f32x4 mfma16(bf16x8 a, bf16x8 b, f32x4 c) {
    return __builtin_amdgcn_mfma_f32_16x16x32_bf16(a, b, c, 0, 0, 0);
}
__device__ __forceinline__ void gload_lds16(const u16* g, u16* l) {
    __builtin_amdgcn_global_load_lds(
        (const __attribute__((address_space(1))) unsigned int*)(g),
        (__attribute__((address_space(3))) unsigned int*)(l), 16, 0, 0);
}

// ---------- problem constants ----------
#define T_TOK 8192
#define DM 768
#define NH 12
#define DH 64
#define DMLP 3072
#define SEQ 1024
#define QKV_LD 2304
#define QK_LD 1536

// ---------- ws arena (u16 offsets) ----------
#define OFF_WQKV ((size_t)0)
#define OFF_WO   (OFF_WQKV + (size_t)2304*768)
#define OFF_WIN  (OFF_WO   + (size_t)768*768)
#define OFF_WOUT (OFF_WIN  + (size_t)768*3072)
#define OFF_BQKV (OFF_WOUT + (size_t)3072*768)          // float[2304] = 4608 u16
#define P0       (OFF_BQKV + (size_t)4608)

#define SZ_N    ((size_t)T_TOK*DM)        // 6,291,456
#define SZ_QKV  ((size_t)T_TOK*QKV_LD)    // 18,874,368 (= QK buf + VtG, exactly)
// Path A: resid_mid lives in d_out (fp32). Peak = P0 + nbuf + qkv + z = 77.1 MB
#define A_NBUF   (P0)
#define A_QKV    (P0 + SZ_N)
#define A_Z      (P0 + SZ_N + SZ_QKV)
#define A_N2     (P0)                       // overlays nbuf (dead after QKV GEMM)
#define A_POST   (P0 + SZ_N)                // overlays qkv+z (dead after O-proj)
#define PATHA_BYTES (((size_t)(P0 + SZ_N + SZ_QKV + SZ_N)) * 2)
// Path B: per-batch attention, 2048-row MLP chunks. Peak = 44.0 MB
#define B_Z      (P0)
#define B_QKVB   (P0 + SZ_N)
#define B_NBUF   (B_QKVB + (size_t)SEQ*QKV_LD)
#define B_N2     (P0)                       // overlays z (dead after O-proj)
#define B_POSTC  (P0 + SZ_N)                // overlays qkvb+nbuf (dead after loop)

// ---------- prep + ln1 fused: weight transposes + bias concat + ln1 ----------
// prep blocks [0, TT_WOUT]: tiled-LDS transposes (R10, coalesced) + bias.
// blocks (TT_WOUT, TT_WOUT+8192]: ln1 on token (bid - TT_WOUT - 1).
// prep and ln1 are independent -> one launch overlaps them and drops a gap.
#define TT_QKV  432
#define TT_WO   (TT_QKV + 144)
#define TT_WIN  (TT_WO + 576)
#define TT_WOUT (TT_WIN + 576)              // = 1728

__global__ __launch_bounds__(256) void prep_kernel(
    const float* __restrict__ WQ, const float* __restrict__ WK, const float* __restrict__ WV,
    const float* __restrict__ WO, const float* __restrict__ Win, const float* __restrict__ Wout,
    const float* __restrict__ bQ, const float* __restrict__ bK, const float* __restrict__ bV,
    u16* __restrict__ Wqkv_t, u16* __restrict__ Wo_t, u16* __restrict__ Win_t,
    u16* __restrict__ Wout_t, float* __restrict__ bias_qkv,
    const float* __restrict__ lnx, const float* __restrict__ lnw,
    const float* __restrict__ lnb, u16* __restrict__ lnout)
{
    const int bid = blockIdx.x;
    const int tid = threadIdx.x;

    if (bid > TT_WOUT) {                    // ---- ln1 branch ----
        __shared__ float red[4];
        size_t base = (size_t)(bid - TT_WOUT - 1) * DM;
        float v0 = lnx[base + tid], v1 = lnx[base + tid + 256], v2 = lnx[base + tid + 512];
        float s = v0 + v1 + v2;
#pragma unroll
        for (int off = 32; off > 0; off >>= 1) s += __shfl_xor(s, off);
        if ((tid & 63) == 0) red[tid >> 6] = s;
        __syncthreads();
        float mu = (red[0] + red[1] + red[2] + red[3]) * (1.0f / 768.0f);
        v0 -= mu; v1 -= mu; v2 -= mu;
        float q = v0 * v0 + v1 * v1 + v2 * v2;
        __syncthreads();
#pragma unroll
        for (int off = 32; off > 0; off >>= 1) q += __shfl_xor(q, off);
        if ((tid & 63) == 0) red[tid >> 6] = q;
        __syncthreads();
        float var = (red[0] + red[1] + red[2] + red[3]) * (1.0f / 768.0f);
        float sc = rsqrtf(var + 1e-5f);
        lnout[base + tid]       = f2b(v0 * sc * lnw[tid]       + lnb[tid]);
        lnout[base + tid + 256] = f2b(v1 * sc * lnw[tid + 256] + lnb[tid + 256]);
        lnout[base + tid + 512] = f2b(v2 * sc * lnw[tid + 512] + lnb[tid + 512]);
        return;
    }
    if (bid == TT_WOUT) {                   // ---- bias concat ----
        for (int j = tid; j < 2304; j += 256)
            bias_qkv[j] = (j < 768) ? bQ[j] : ((j < 1536) ? bK[j - 768] : bV[j - 1536]);
        return;
    }
    // ---- weight transpose tiles ----
    __shared__ u16 tile[64][72];            // [out-row][out-col], pad 72

    const float* sp; u16* dp;
    int sldc, dldc;
    if (bid < TT_QKV) {
        int wh = bid / 12, td = bid % 12;
        int which = wh / 12, h = wh % 12;
        const float* W = (which == 0) ? WQ : ((which == 1) ? WK : WV);
        sp = W + (size_t)h * 49152 + (size_t)(td * 64) * 64;   sldc = 64;
        dp = Wqkv_t + (size_t)(which * 768 + h * 64) * 768 + td * 64; dldc = 768;
    } else if (bid < TT_WO) {
        int t2 = bid - TT_QKV, ti = t2 / 12, tj = t2 % 12;
        sp = WO + (size_t)(ti * 64) * 768 + tj * 64;           sldc = 768;
        dp = Wo_t + (size_t)(tj * 64) * 768 + ti * 64;         dldc = 768;
    } else if (bid < TT_WIN) {
        int t3 = bid - TT_WO, ti = t3 / 48, tj = t3 % 48;
        sp = Win + (size_t)(ti * 64) * 3072 + tj * 64;         sldc = 3072;
        dp = Win_t + (size_t)(tj * 64) * 768 + ti * 64;        dldc = 768;
    } else {
        int t4 = bid - TT_WIN, ti = t4 / 12, tj = t4 % 12;
        sp = Wout + (size_t)(ti * 64) * 768 + tj * 64;         sldc = 768;
        dp = Wout_t + (size_t)(tj * 64) * 3072 + ti * 64;      dldc = 3072;
    }

    {
        int r = tid >> 2, cseg = (tid & 3) * 16;
        const float* src = sp + (size_t)r * sldc + cseg;
#pragma unroll
        for (int j = 0; j < 16; j++)
            tile[cseg + j][r] = f2b(src[j]);    // transposed store
    }
    __syncthreads();
    {
        int r2 = tid >> 2, c2seg = (tid & 3) * 16;
        u16* dst = dp + (size_t)r2 * dldc + c2seg;
        *(u16x8*)dst       = *(const u16x8*)&tile[r2][c2seg];
        *(u16x8*)(dst + 8) = *(const u16x8*)&tile[r2][c2seg + 8];
    }
}

// ---------- layernorm (block per token), fp32 in -> bf16 out (ln2) ----------
__global__ __launch_bounds__(256) void ln_kernel(
    const float* __restrict__ x, const float* __restrict__ w,
    const float* __restrict__ bb, u16* __restrict__ out)
{
    __shared__ float red[4];
    size_t base = (size_t)blockIdx.x * DM;
    int tid = threadIdx.x;
    float v0 = x[base + tid], v1 = x[base + tid + 256], v2 = x[base + tid + 512];
    float s = v0 + v1 + v2;
#pragma unroll
    for (int off = 32; off > 0; off >>= 1) s += __shfl_xor(s, off);
    if ((tid & 63) == 0) red[tid >> 6] = s;
    __syncthreads();
    float mu = (red[0] + red[1] + red[2] + red[3]) * (1.0f / 768.0f);
    v0 -= mu; v1 -= mu; v2 -= mu;
    float q = v0 * v0 + v1 * v1 + v2 * v2;
    __syncthreads();
#pragma unroll
    for (int off = 32; off > 0; off >>= 1) q += __shfl_xor(q, off);
    if ((tid & 63) == 0) red[tid >> 6] = q;
    __syncthreads();
    float var = (red[0] + red[1] + red[2] + red[3]) * (1.0f / 768.0f);
    float sc = rsqrtf(var + 1e-5f);
    out[base + tid]       = f2b(v0 * sc * w[tid]       + bb[tid]);
    out[base + tid + 256] = f2b(v1 * sc * w[tid + 256] + bb[tid + 256]);
    out[base + tid + 512] = f2b(v2 * sc * w[tid + 512] + bb[tid + 512]);
}

// ---------- GEMM: C[M][N] = A[M][K] @ BT[N][K]^T ----------
// EXACT R6 config (proven best; frozen — depth-4/persistent/wide-N all lost).
// Counted-vmcnt 3-buf pipeline: stage tile t+2 after compute of t; per-iter
// sync = s_waitcnt vmcnt(LPT) + raw s_barrier + sched_barrier(0).
// Transposed-C fragments for EPI 0..3 -> u16x4/f32x4 vector epilogues.
// EPI 4: QKV split; Q cols (<768) pre-scaled by 0.125 (exact bf16 pow2) so
// attn's softmax chain drops its scale multiply.
template <int EPI, int TM>
__global__ __launch_bounds__(256) void gemm_bt_kernel(
    const u16* __restrict__ A, const u16* __restrict__ BT,
    const float* __restrict__ bias, const float* __restrict__ aux,
    void* __restrict__ outp, int N, int K)
{
    __shared__ __align__(16) u16 As[3][TM * 32];
    __shared__ __align__(16) u16 Bs[3][128 * 32];
    const int tid = threadIdx.x;
    const int w = tid >> 6, l = tid & 63;
    const int lr = l & 15, lq = l >> 4;
    const int bm = blockIdx.x * TM, bn = blockIdx.y * 128;
    constexpr int MT = TM / 32;                 // m-frags per wave (4 or 2)
    constexpr bool TR = (EPI != 4);             // transposed-C fragments
    const int wm = (w >> 1) * (TM / 2), wn = (w & 1) * 64;

    f32x4 acc[MT][4];
#pragma unroll
    for (int i = 0; i < MT; i++)
#pragma unroll
        for (int j = 0; j < 4; j++) acc[i][j] = f32x4{0.f, 0.f, 0.f, 0.f};

    const int srow_a = (TM == 128) ? (w * 32 + (l >> 2)) : (w * 16 + (l >> 2));
    const int srow_b = w * 32 + (l >> 2);
    const int scol = (l & 3) * 8;
    const u16* Ab = A  + (size_t)(bm + srow_a) * K + scol;
    const u16* Bb = BT + (size_t)(bn + srow_b) * K + scol;
    const int asd = (TM == 128) ? w * 1024 : w * 512;
    const int bsd = w * 1024;

    const int kiter = K >> 5;                   // >= 24 for all our shapes

#define STAGE_T(kk, s)                                                      \
    {   const int k0_ = (kk) * 32;                                          \
        gload_lds16(Ab + k0_, &As[s][asd]);                                 \
        if constexpr (TM == 128) gload_lds16(Ab + 16 * K + k0_, &As[s][asd + 512]); \
        gload_lds16(Bb + k0_,          &Bs[s][bsd]);                        \
        gload_lds16(Bb + 16 * K + k0_, &Bs[s][bsd + 512]);  }

    // prologue: stage tiles 0 and 1 (depth-2 ahead)
    STAGE_T(0, 0);
    STAGE_T(1, 1);

    int cur = 0;
    for (int t = 0; t < kiter; ++t) {
        // wait: tile t's loads complete; tile t+1's (newest LPT) may stay in flight
        if (t + 1 < kiter) {
            if constexpr (TM == 128) asm volatile("s_waitcnt vmcnt(4)" ::: "memory");
            else                     asm volatile("s_waitcnt vmcnt(3)" ::: "memory");
        } else {
            asm volatile("s_waitcnt vmcnt(0)" ::: "memory");
        }
        __builtin_amdgcn_s_barrier();
        __builtin_amdgcn_sched_barrier(0);      // pin: nothing moves across sync point

        const u16* Asc = &As[cur][0];
        const u16* Bsc = &Bs[cur][0];
        bf16x8 af[MT], bf[4];
#pragma unroll
        for (int mt = 0; mt < MT; mt++) af[mt] = ldfrag(&Asc[(wm + mt * 16 + lr) * 32 + lq * 8]);
#pragma unroll
        for (int nt = 0; nt < 4; nt++) bf[nt] = ldfrag(&Bsc[(wn + nt * 16 + lr) * 32 + lq * 8]);
#pragma unroll
        for (int mt = 0; mt < MT; mt++)
#pragma unroll
            for (int nt = 0; nt < 4; nt++)
                acc[mt][nt] = TR ? mfma16(bf[nt], af[mt], acc[mt][nt])
                                 : mfma16(af[mt], bf[nt], acc[mt][nt]);

        if (t + 2 < kiter) {                    // stage t+2 into the buffer freed at t-1
            int nb = cur + 2; if (nb >= 3) nb -= 3;
            STAGE_T(t + 2, nb);
        }
        cur = (cur + 1 == 3) ? 0 : cur + 1;
    }
#undef STAGE_T

    if (EPI == 4) {
        // original orientation: acc[mt][nt][r] = C[row=lq*4+r within mt][col=lr within nt]
        const bool isv = (bn >= 1536);
        u16* vtg = (u16*)aux;             // VtG base (u16), passed via aux
#pragma unroll
        for (int mt = 0; mt < MT; mt++) {
            int row0 = bm + wm + mt * 16 + lq * 4;
            if (!isv) {
#pragma unroll
                for (int r = 0; r < 4; r++) {
                    size_t ro = (size_t)(row0 + r) * QK_LD;
#pragma unroll
                    for (int nt = 0; nt < 4; nt++) {
                        int col = bn + wn + nt * 16 + lr;
                        float v = acc[mt][nt][r] + bias[col];
                        if (col < 768) v *= 0.125f;     // pre-scale Q (exact pow2)
                        ((u16*)outp)[ro + col] = f2b(v);
                    }
                }
            } else {
                int bloc = row0 >> 10;          // batch within this buffer
                int s = row0 & 1023;            // seq position (multiple of 4)
#pragma unroll
                for (int nt = 0; nt < 4; nt++) {
                    int col = bn + wn + nt * 16 + lr;
                    int he = col - 1536;        // h*64 + e
                    float bcol = bias[col];
                    u16x4 pk;
                    pk[0] = f2b(acc[mt][nt][0] + bcol);
                    pk[1] = f2b(acc[mt][nt][1] + bcol);
                    pk[2] = f2b(acc[mt][nt][2] + bcol);
                    pk[3] = f2b(acc[mt][nt][3] + bcol);
                    *(u16x4*)&vtg[(size_t)bloc * (NH * 64 * SEQ)
                                  + (size_t)he * SEQ + s] = pk;
                }
            }
        }
        return;
    }

    // transposed-C epilogue: thread holds row = wm+mt*16+lr,
    // cols = wn+nt*16+lq*4 .. +3  -> fully vectorized stores.
#pragma unroll
    for (int mt = 0; mt < MT; mt++) {
        int row = bm + wm + mt * 16 + lr;
        size_t ro = (size_t)row * N;
#pragma unroll
        for (int nt = 0; nt < 4; nt++) {
            int col0 = bn + wn + nt * 16 + lq * 4;
            f32x4 v = acc[mt][nt] + *(const f32x4*)&bias[col0];
            if (EPI == 0) {
                u16x4 pk;
#pragma unroll
                for (int r = 0; r < 4; r++) pk[r] = f2b(v[r]);
                *(u16x4*)&((u16*)outp)[ro + col0] = pk;
            } else if (EPI == 2) {
                u16x4 pk;
#pragma unroll
                for (int r = 0; r < 4; r++) {
                    float x = v[r];
                    float y = 0.7978845608028654f * (x + 0.044715f * x * x * x);
                    pk[r] = f2b(x / (1.0f + __expf(-2.0f * y)));
                }
                *(u16x4*)&((u16*)outp)[ro + col0] = pk;
            } else {  // EPI 1 / 3: fp32 out = v + aux
                f32x4 a4 = *(const f32x4*)&aux[ro + col0];
                v += a4;
                *(f32x4*)&((float*)outp)[ro + col0] = v;
            }
        }
    }
}

// ---------- flash attention (MFMA): block = (64 q-rows, batch*head) ----------
// R6 structure (proven) + R12 tweaks:
//  - Path A XCD-chunk swizzle (T1): all 16 qt-blocks of one (b,h) K/V panel
//    land on ONE XCD -> panel fetched once per chip, not once per XCD.
//  - exact skip-rescale: if no lane's row-max grows, alpha==1 exactly ->
//    skip exp + 4 shfl broadcasts + 16 O-mults (wave-uniform branch).
//  - T5 setprio(1) around QK and PV MFMA clusters (m191: +4-7% attn).
//  - softmax scale folded into Q upstream (EPI-4), so no *0.125 here.
__global__ __launch_bounds__(256, 5) void attn_kernel(
    const u16* __restrict__ qk, const u16* __restrict__ vtg,
    u16* __restrict__ z, int b0, int bq0)
{
    __shared__ __align__(16) u16 Ks[64 * 72];
    __shared__ __align__(16) u16 Vt[64 * 72];
    __shared__ __align__(16) u16 Ps[4][16 * 72];

    int qt, bh;
    if (gridDim.y == 96) {                  // Path A: XCD-chunked (bijective)
        int F = (int)(blockIdx.y * gridDim.x + blockIdx.x);  // HW dispatch order
        int xcd = F & 7, idx = F >> 3;      // idx in [0,192)
        bh = xcd * 12 + (idx >> 4);         // 12 panels per XCD
        qt = 15 - (idx & 15);               // heavy-first within panel
    } else {
        qt = (int)(gridDim.x - 1) - (int)blockIdx.x;   // heavy blocks first
        bh = blockIdx.y;
    }
    const int b = b0 + bh / NH, h = bh % NH;
    const int tid = threadIdx.x, w = tid >> 6, l = tid & 63;
    const int lr = l & 15, lq = l >> 4;
    const int qbase = qt * 64;
    const u16* qp = qk + (size_t)(b - bq0) * SEQ * QK_LD + h * 64;
    const u16* kp = qp + 768;
    const u16* vthead = vtg + ((size_t)(b - bq0) * NH + h) * (64 * SEQ);
    u16* PsW = &Ps[w][0];

    // Q fragments in registers (B-operand of swapped QK): row w*16+lr, k-slice lq*8
    bf16x8 aq0, aq1;
    {
        const u16* qrow = qp + (size_t)(qbase + w * 16 + lr) * QK_LD + lq * 8;
        aq0 = ldfrag(qrow);
        aq1 = ldfrag(qrow + 32);
    }

    float m_i = -1e30f;       // running max for q = w*16 + lr (softmax domain)
    float l_i = 0.f;          // running denom for q = w*16 + lr
    f32x4 O[4];
#pragma unroll
    for (int i = 0; i < 4; i++) O[i] = f32x4{0.f, 0.f, 0.f, 0.f};

    const int nkt = qt + 1;                 // causal: tiles 0..qt
    const int srow = tid >> 2;              // 0..63  (K row / V e-row)
    const int spart = (tid & 3) * 16;       // 0,16,32,48

    // prefetch tile 0 into registers (T14: issue-early / write-late)
    u16x8 kreg0, kreg1, vreg0, vreg1;
    {
        const u16* ks = kp + (size_t)srow * QK_LD + spart;
        kreg0 = *(const u16x8*)ks;
        kreg1 = *(const u16x8*)(ks + 8);
        const u16* vs = vthead + (size_t)srow * SEQ + spart;
        vreg0 = *(const u16x8*)vs;
        vreg1 = *(const u16x8*)(vs + 8);
    }

    for (int kt = 0; kt < nkt; ++kt) {
        __syncthreads();                    // prev tile's MFMAs done reading Ks/Vt
        *(u16x8*)&Ks[srow * 72 + spart]     = kreg0;
        *(u16x8*)&Ks[srow * 72 + spart + 8] = kreg1;
        *(u16x8*)&Vt[srow * 72 + spart]     = vreg0;
        *(u16x8*)&Vt[srow * 72 + spart + 8] = vreg1;
        __syncthreads();
        if (kt + 1 < nkt) {                 // issue next-tile loads; latency hides under compute
            const u16* ks = kp + (size_t)((kt + 1) * 64 + srow) * QK_LD + spart;
            kreg0 = *(const u16x8*)ks;
            kreg1 = *(const u16x8*)(ks + 8);
            const u16* vs = vthead + (size_t)srow * SEQ + (kt + 1) * 64 + spart;
            vreg0 = *(const u16x8*)vs;
            vreg1 = *(const u16x8*)(vs + 8);
        }

        // ---- swapped QK^T: S^T[k][q], lane holds q = lr, k = nt*16 + lq*4 + r ----
        f32x4 S[4];
#pragma unroll
        for (int nt = 0; nt < 4; nt++) S[nt] = f32x4{0.f, 0.f, 0.f, 0.f};
        __builtin_amdgcn_s_setprio(1);
#pragma unroll
        for (int nt = 0; nt < 4; nt++) {
            bf16x8 bk0 = ldfrag(&Ks[(nt * 16 + lr) * 72 + lq * 8]);
            bf16x8 bk1 = ldfrag(&Ks[(nt * 16 + lr) * 72 + 32 + lq * 8]);
            S[nt] = mfma16(bk0, aq0, S[nt]);
            S[nt] = mfma16(bk1, aq1, S[nt]);
        }
        __builtin_amdgcn_s_setprio(0);

        // ---- online softmax, lane-local per q-row (mask only on diag tile) ----
        const bool diag = (kt == qt);
        float mx = -1e30f;
#pragma unroll
        for (int nt = 0; nt < 4; nt++)
#pragma unroll
            for (int r = 0; r < 4; r++) {
                float sv = S[nt][r];        // Q pre-scaled upstream
                if (diag) sv = (nt * 16 + lq * 4 + r <= w * 16 + lr) ? sv : -1e30f;
                S[nt][r] = sv;
                mx = fmaxf(mx, sv);
            }
        mx = fmaxf(mx, __shfl_xor(mx, 16));
        mx = fmaxf(mx, __shfl_xor(mx, 32));
        const bool need = __any(mx > m_i);  // wave-uniform; exact skip when false
        float mn = m_i, alpha = 1.f;
        if (need) {
            mn = fmaxf(m_i, mx);
            alpha = __expf(m_i - mn);
            m_i = mn;
        }
        float rs = 0.f;
#pragma unroll
        for (int nt = 0; nt < 4; nt++) {
            u16x4 pk;
#pragma unroll
            for (int r = 0; r < 4; r++) {
                float pe = __expf(S[nt][r] - mn);
                rs += pe;
                pk[r] = f2b(pe);
            }
            // Ps[q = lr][k = nt*16 + lq*4 .. +3], 8B aligned
            *(u16x4*)&PsW[lr * 72 + nt * 16 + lq * 4] = pk;
        }
        rs += __shfl_xor(rs, 16);
        rs += __shfl_xor(rs, 32);
        if (need) {
            l_i = l_i * alpha + rs;
            // ---- rescale O (O-domain: lane holds e = lr, q rows lq*4+r) ----
#pragma unroll
            for (int r = 0; r < 4; r++) {
                float ar = __shfl(alpha, (l & 48) | (lq * 4 + r));
                O[0][r] *= ar; O[1][r] *= ar; O[2][r] *= ar; O[3][r] *= ar;
            }
        } else {
            l_i += rs;
        }

        // ---- PV (Ps is wave-private: no barrier, only lgkmcnt) ----
        __builtin_amdgcn_s_setprio(1);
#pragma unroll
        for (int kq = 0; kq < 2; kq++) {
            bf16x8 ap = ldfrag(&PsW[lr * 72 + kq * 32 + lq * 8]);
#pragma unroll
            for (int ot = 0; ot < 4; ot++) {
                bf16x8 bv = ldfrag(&Vt[(ot * 16 + lr) * 72 + kq * 32 + lq * 8]);
                O[ot] = mfma16(ap, bv, O[ot]);
            }
        }
        __builtin_amdgcn_s_setprio(0);
    }

    // ---- epilogue: bring l_i to O-domain, divide, store ----
    float li[4];
#pragma unroll
    for (int r = 0; r < 4; r++)
        li[r] = __shfl(l_i, (l & 48) | (lq * 4 + r));
#pragma unroll
    for (int ot = 0; ot < 4; ot++)
#pragma unroll
        for (int r = 0; r < 4; r++) {
            int q = qbase + w * 16 + lq * 4 + r;
            size_t t = (size_t)b * SEQ + q;
            z[t * DM + h * 64 + ot * 16 + lr] = f2b(O[ot][r] / li[r]);
        }
}

// ---------- launch ----------
extern "C" void kernel_launch(void* const* d_in, const int* in_sizes, int n_in,
                              void* d_out, int out_size, void* d_ws, size_t ws_size,
                              hipStream_t stream) {
    const float* resid_pre = (const float*)d_in[0];
    const float* W_Q  = (const float*)d_in[1];
    const float* b_Q  = (const float*)d_in[2];
    const float* W_K  = (const float*)d_in[3];
    const float* b_K  = (const float*)d_in[4];
    const float* W_V  = (const float*)d_in[5];
    const float* b_V  = (const float*)d_in[6];
    const float* W_O  = (const float*)d_in[7];
    const float* b_O  = (const float*)d_in[8];
    const float* ln1w = (const float*)d_in[9];
    const float* ln1b = (const float*)d_in[10];
    const float* ln2w = (const float*)d_in[11];
    const float* ln2b = (const float*)d_in[12];
    const float* W_in  = (const float*)d_in[13];
    const float* b_in  = (const float*)d_in[14];
    const float* W_out = (const float*)d_in[15];
    const float* b_out = (const float*)d_in[16];

    u16* ws16       = (u16*)d_ws;
    u16* Wqkv_t     = ws16 + OFF_WQKV;
    u16* Wo_t       = ws16 + OFF_WO;
    u16* Win_t      = ws16 + OFF_WIN;
    u16* Wout_t     = ws16 + OFF_WOUT;
    float* bias_qkv = (float*)(ws16 + OFF_BQKV);
    float* outp  = (float*)d_out;    // fp32 output (reference dtype)
    float* resid = (float*)d_out;    // resid_mid lives in d_out until final add

    if (ws_size >= PATHA_BYTES) {
        // ---- Path A (77 MB ws) ----
        u16* nbuf    = ws16 + A_NBUF;
        u16* qkbuf   = ws16 + A_QKV;                          // [8192][1536] bf16
        u16* vtgA    = ws16 + A_QKV + (size_t)T_TOK * QK_LD;  // [8][12][64][1024] bf16
        u16* zbuf    = ws16 + A_Z;
        u16* n2buf   = ws16 + A_N2;
        u16* postbuf = ws16 + A_POST;

        prep_kernel<<<TT_WOUT + 1 + T_TOK, 256, 0, stream>>>(
            W_Q, W_K, W_V, W_O, W_in, W_out, b_Q, b_K, b_V,
            Wqkv_t, Wo_t, Win_t, Wout_t, bias_qkv,
            resid_pre, ln1w, ln1b, nbuf);
        gemm_bt_kernel<4, 128><<<dim3(T_TOK / 128, QKV_LD / 128), 256, 0, stream>>>(
            nbuf, Wqkv_t, bias_qkv, (const float*)vtgA, qkbuf, QKV_LD, DM);
        attn_kernel<<<dim3(SEQ / 64, 8 * NH), 256, 0, stream>>>(qkbuf, vtgA, zbuf, 0, 0);
        gemm_bt_kernel<1, 64><<<dim3(T_TOK / 64, DM / 128), 256, 0, stream>>>(
            zbuf, Wo_t, b_O, resid_pre, resid, DM, DM);
        ln_kernel<<<T_TOK, 256, 0, stream>>>(resid, ln2w, ln2b, n2buf);
        gemm_bt_kernel<2, 128><<<dim3(T_TOK / 128, DMLP / 128), 256, 0, stream>>>(
            n2buf, Win_t, b_in, nullptr, postbuf, DMLP, DM);
        gemm_bt_kernel<3, 64><<<dim3(T_TOK / 64, DM / 128), 256, 0, stream>>>(
            postbuf, Wout_t, b_out, resid, outp, DM, DMLP);
    } else {
        // ---- Path B (44 MB ws): per-batch attention, chunked MLP ----
        u16* zbuf   = ws16 + B_Z;
        u16* qkb    = ws16 + B_QKVB;                          // [1024][1536] bf16
        u16* vtgB   = qkb + (size_t)SEQ * QK_LD;              // [12][64][1024] bf16
        u16* nbuf   = ws16 + B_NBUF;
        u16* n2buf  = ws16 + B_N2;
        u16* postc  = ws16 + B_POSTC;

        prep_kernel<<<TT_WOUT + 1 + T_TOK, 256, 0, stream>>>(
            W_Q, W_K, W_V, W_O, W_in, W_out, b_Q, b_K, b_V,
            Wqkv_t, Wo_t, Win_t, Wout_t, bias_qkv,
            resid_pre, ln1w, ln1b, nbuf);
        for (int b = 0; b < 8; b++) {
            gemm_bt_kernel<4, 128><<<dim3(SEQ / 128, QKV_LD / 128), 256, 0, stream>>>(
                nbuf + (size_t)b * SEQ * DM, Wqkv_t, bias_qkv, (const float*)vtgB, qkb, QKV_LD, DM);
            attn_kernel<<<dim3(SEQ / 64, NH), 256, 0, stream>>>(qkb, vtgB, zbuf, b, b);
        }
        gemm_bt_kernel<1, 64><<<dim3(T_TOK / 64, DM / 128), 256, 0, stream>>>(
            zbuf, Wo_t, b_O, resid_pre, resid, DM, DM);
        ln_kernel<<<T_TOK, 256, 0, stream>>>(resid, ln2w, ln2b, n2buf);
        for (int c = 0; c < 4; c++) {
            const size_t r0 = (size_t)c * 2048;
            gemm_bt_kernel<2, 128><<<dim3(2048 / 128, DMLP / 128), 256, 0, stream>>>(
                n2buf + r0 * DM, Win_t, b_in, nullptr, postc, DMLP, DM);
            gemm_bt_kernel<3, 64><<<dim3(2048 / 64, DM / 128), 256, 0, stream>>>(
                postc, Wout_t, b_out, resid + r0 * DM, outp + r0 * DM, DM, DMLP);
        }
    }
}

// Round 13
// 365.189 us; speedup vs baseline: 1.2136x; 1.0450x over previous
//
#include <hip/hip_runtime.h>
#include <hip/hip_bf16.h>

// ---------- types / helpers ----------
typedef unsigned short u16;
typedef float f32x4 __attribute__((ext_vector_type(4)));
typedef __bf16 bf16x8 __attribute__((ext_vector_type(8)));
typedef unsigned short u16x8 __attribute__((ext_vector_type(8)));
typedef unsigned short u16x4 __attribute__((ext_vector_type(4)));

__device__ __forceinline__ float b2f(u16 u) {
    unsigned v = ((unsigned)u) << 16;
    return __builtin_bit_cast(float, v);
}
__device__ __forceinline__ u16 f2b(float f) {
    unsigned u = __builtin_bit_cast(unsigned, f);
    u += 0x7fffu + ((u >> 16) & 1u);   // RNE
    return (u16)(u >> 16);
}
__device__ __forceinline__ bf16x8 ldfrag(const u16* p) {
    return __builtin_bit_cast(bf16x8, *(const u16x8*)p);
}
__device__ __forceinline__ f32x4 mfma16(bf16x8 a, bf16x8 b, f32x4 c) {
    return __builtin_amdgcn_mfma_f32_16x16x32_bf16(a, b, c, 0, 0, 0);
}
__device__ __forceinline__ void gload_lds16(const u16* g, u16* l) {
    __builtin_amdgcn_global_load_lds(
        (const __attribute__((address_space(1))) unsigned int*)(g),
        (__attribute__((address_space(3))) unsigned int*)(l), 16, 0, 0);
}

// ---------- problem constants ----------
#define T_TOK 8192
#define DM 768
#define NH 12
#define DH 64
#define DMLP 3072
#define SEQ 1024
#define QKV_LD 2304
#define QK_LD 1536

// ---------- ws arena (u16 offsets) ----------
#define OFF_WQKV ((size_t)0)
#define OFF_WO   (OFF_WQKV + (size_t)2304*768)
#define OFF_WIN  (OFF_WO   + (size_t)768*768)
#define OFF_WOUT (OFF_WIN  + (size_t)768*3072)
#define OFF_BQKV (OFF_WOUT + (size_t)3072*768)          // float[2304] = 4608 u16
#define P0       (OFF_BQKV + (size_t)4608)

#define SZ_N    ((size_t)T_TOK*DM)        // 6,291,456
#define SZ_QKV  ((size_t)T_TOK*QKV_LD)    // 18,874,368 (= QK buf + VtG, exactly)
// Path A: resid_mid lives in d_out (fp32). Peak = P0 + nbuf + qkv + z = 77.1 MB
#define A_NBUF   (P0)
#define A_QKV    (P0 + SZ_N)
#define A_Z      (P0 + SZ_N + SZ_QKV)
#define A_N2     (P0)                       // overlays nbuf (dead after QKV GEMM)
#define A_POST   (P0 + SZ_N)                // overlays qkv+z (dead after O-proj)
#define PATHA_BYTES (((size_t)(P0 + SZ_N + SZ_QKV + SZ_N)) * 2)
// Path B: per-batch attention, 2048-row MLP chunks. Peak = 44.0 MB
#define B_Z      (P0)
#define B_QKVB   (P0 + SZ_N)
#define B_NBUF   (B_QKVB + (size_t)SEQ*QKV_LD)
#define B_N2     (P0)                       // overlays z (dead after O-proj)
#define B_POSTC  (P0 + SZ_N)                // overlays qkvb+nbuf (dead after loop)

// ---------- prep + ln1 fused: weight transposes + bias concat + ln1 ----------
#define TT_QKV  432
#define TT_WO   (TT_QKV + 144)
#define TT_WIN  (TT_WO + 576)
#define TT_WOUT (TT_WIN + 576)              // = 1728

__global__ __launch_bounds__(256) void prep_kernel(
    const float* __restrict__ WQ, const float* __restrict__ WK, const float* __restrict__ WV,
    const float* __restrict__ WO, const float* __restrict__ Win, const float* __restrict__ Wout,
    const float* __restrict__ bQ, const float* __restrict__ bK, const float* __restrict__ bV,
    u16* __restrict__ Wqkv_t, u16* __restrict__ Wo_t, u16* __restrict__ Win_t,
    u16* __restrict__ Wout_t, float* __restrict__ bias_qkv,
    const float* __restrict__ lnx, const float* __restrict__ lnw,
    const float* __restrict__ lnb, u16* __restrict__ lnout)
{
    const int bid = blockIdx.x;
    const int tid = threadIdx.x;

    if (bid > TT_WOUT) {                    // ---- ln1 branch ----
        __shared__ float red[4];
        size_t base = (size_t)(bid - TT_WOUT - 1) * DM;
        float v0 = lnx[base + tid], v1 = lnx[base + tid + 256], v2 = lnx[base + tid + 512];
        float s = v0 + v1 + v2;
#pragma unroll
        for (int off = 32; off > 0; off >>= 1) s += __shfl_xor(s, off);
        if ((tid & 63) == 0) red[tid >> 6] = s;
        __syncthreads();
        float mu = (red[0] + red[1] + red[2] + red[3]) * (1.0f / 768.0f);
        v0 -= mu; v1 -= mu; v2 -= mu;
        float q = v0 * v0 + v1 * v1 + v2 * v2;
        __syncthreads();
#pragma unroll
        for (int off = 32; off > 0; off >>= 1) q += __shfl_xor(q, off);
        if ((tid & 63) == 0) red[tid >> 6] = q;
        __syncthreads();
        float var = (red[0] + red[1] + red[2] + red[3]) * (1.0f / 768.0f);
        float sc = rsqrtf(var + 1e-5f);
        lnout[base + tid]       = f2b(v0 * sc * lnw[tid]       + lnb[tid]);
        lnout[base + tid + 256] = f2b(v1 * sc * lnw[tid + 256] + lnb[tid + 256]);
        lnout[base + tid + 512] = f2b(v2 * sc * lnw[tid + 512] + lnb[tid + 512]);
        return;
    }
    if (bid == TT_WOUT) {                   // ---- bias concat ----
        for (int j = tid; j < 2304; j += 256)
            bias_qkv[j] = (j < 768) ? bQ[j] : ((j < 1536) ? bK[j - 768] : bV[j - 1536]);
        return;
    }
    // ---- weight transpose tiles ----
    __shared__ u16 tile[64][72];            // [out-row][out-col], pad 72

    const float* sp; u16* dp;
    int sldc, dldc;
    if (bid < TT_QKV) {
        int wh = bid / 12, td = bid % 12;
        int which = wh / 12, h = wh % 12;
        const float* W = (which == 0) ? WQ : ((which == 1) ? WK : WV);
        sp = W + (size_t)h * 49152 + (size_t)(td * 64) * 64;   sldc = 64;
        dp = Wqkv_t + (size_t)(which * 768 + h * 64) * 768 + td * 64; dldc = 768;
    } else if (bid < TT_WO) {
        int t2 = bid - TT_QKV, ti = t2 / 12, tj = t2 % 12;
        sp = WO + (size_t)(ti * 64) * 768 + tj * 64;           sldc = 768;
        dp = Wo_t + (size_t)(tj * 64) * 768 + ti * 64;         dldc = 768;
    } else if (bid < TT_WIN) {
        int t3 = bid - TT_WO, ti = t3 / 48, tj = t3 % 48;
        sp = Win + (size_t)(ti * 64) * 3072 + tj * 64;         sldc = 3072;
        dp = Win_t + (size_t)(tj * 64) * 768 + ti * 64;        dldc = 768;
    } else {
        int t4 = bid - TT_WIN, ti = t4 / 12, tj = t4 % 12;
        sp = Wout + (size_t)(ti * 64) * 768 + tj * 64;         sldc = 768;
        dp = Wout_t + (size_t)(tj * 64) * 3072 + ti * 64;      dldc = 3072;
    }

    {
        int r = tid >> 2, cseg = (tid & 3) * 16;
        const float* src = sp + (size_t)r * sldc + cseg;
#pragma unroll
        for (int j = 0; j < 16; j++)
            tile[cseg + j][r] = f2b(src[j]);    // transposed store
    }
    __syncthreads();
    {
        int r2 = tid >> 2, c2seg = (tid & 3) * 16;
        u16* dst = dp + (size_t)r2 * dldc + c2seg;
        *(u16x8*)dst       = *(const u16x8*)&tile[r2][c2seg];
        *(u16x8*)(dst + 8) = *(const u16x8*)&tile[r2][c2seg + 8];
    }
}

// ---------- layernorm (block per token), fp32 in -> bf16 out (ln2) ----------
__global__ __launch_bounds__(256) void ln_kernel(
    const float* __restrict__ x, const float* __restrict__ w,
    const float* __restrict__ bb, u16* __restrict__ out)
{
    __shared__ float red[4];
    size_t base = (size_t)blockIdx.x * DM;
    int tid = threadIdx.x;
    float v0 = x[base + tid], v1 = x[base + tid + 256], v2 = x[base + tid + 512];
    float s = v0 + v1 + v2;
#pragma unroll
    for (int off = 32; off > 0; off >>= 1) s += __shfl_xor(s, off);
    if ((tid & 63) == 0) red[tid >> 6] = s;
    __syncthreads();
    float mu = (red[0] + red[1] + red[2] + red[3]) * (1.0f / 768.0f);
    v0 -= mu; v1 -= mu; v2 -= mu;
    float q = v0 * v0 + v1 * v1 + v2 * v2;
    __syncthreads();
#pragma unroll
    for (int off = 32; off > 0; off >>= 1) q += __shfl_xor(q, off);
    if ((tid & 63) == 0) red[tid >> 6] = q;
    __syncthreads();
    float var = (red[0] + red[1] + red[2] + red[3]) * (1.0f / 768.0f);
    float sc = rsqrtf(var + 1e-5f);
    out[base + tid]       = f2b(v0 * sc * w[tid]       + bb[tid]);
    out[base + tid + 256] = f2b(v1 * sc * w[tid + 256] + bb[tid + 256]);
    out[base + tid + 512] = f2b(v2 * sc * w[tid + 512] + bb[tid + 512]);
}

// ---------- GEMM: C[M][N] = A[M][K] @ BT[N][K]^T ----------
// R6 counted-vmcnt 3-buf pipeline (frozen sync structure) + R13 8-wave
// wide-N variant for the two big GEMMs:
//   TN=256: 512 threads / 8 waves (2x4), per-wave sub-tile still 64x64
//   (acc[4][4], VGPR ~88 — avoids R7's VGPR-152 collapse). LDS 73.7 KB ->
//   2 blocks/CU = 16 waves/CU (vs 12); A-panel refetch halves; staging = 3
//   loads/thread (A:1, B:2). Steady wait vmcnt(3) (LPT=3, same 3-buf proof).
//   TN=128: original 4-wave config for the small-N GEMMs (TM=64).
// Transposed-C fragments for EPI 0..3 -> u16x4/f32x4 vector epilogues.
// EPI 4: QKV split; Q cols (<768) pre-scaled by 0.125 (exact bf16 pow2).
template <int EPI, int TM, int TN>
__global__ __launch_bounds__((TN == 256) ? 512 : 256) void gemm_bt_kernel(
    const u16* __restrict__ A, const u16* __restrict__ BT,
    const float* __restrict__ bias, const float* __restrict__ aux,
    void* __restrict__ outp, int N, int K)
{
    __shared__ __align__(16) u16 As[3][TM * 32];
    __shared__ __align__(16) u16 Bs[3][TN * 32];
    const int tid = threadIdx.x;
    const int w = tid >> 6, l = tid & 63;
    const int lr = l & 15, lq = l >> 4;
    const int bm = blockIdx.x * TM, bn = blockIdx.y * TN;
    constexpr int MT = TM / 32;                 // m-frags per wave (4 or 2)
    constexpr bool TR = (EPI != 4);             // transposed-C fragments
    const int wm = (TN == 256) ? (w >> 2) * 64 : (w >> 1) * (TM / 2);
    const int wn = (TN == 256) ? (w & 3) * 64  : (w & 1) * 64;

    f32x4 acc[MT][4];
#pragma unroll
    for (int i = 0; i < MT; i++)
#pragma unroll
        for (int j = 0; j < 4; j++) acc[i][j] = f32x4{0.f, 0.f, 0.f, 0.f};

    // staging decomposition
    int srow_a, srow_b, scol;
    if constexpr (TN == 256) {
        srow_a = tid >> 2;  srow_b = tid >> 2;  scol = (tid & 3) * 8;   // 512 thr
    } else {
        srow_a = (TM == 128) ? (w * 32 + (l >> 2)) : (w * 16 + (l >> 2));
        srow_b = w * 32 + (l >> 2);
        scol = (l & 3) * 8;
    }
    const u16* Ab = A  + (size_t)(bm + srow_a) * K + scol;
    const u16* Bb = BT + (size_t)(bn + srow_b) * K + scol;
    const int asd = (TN == 256) ? w * 512 : ((TM == 128) ? w * 1024 : w * 512);
    const int bsd = (TN == 256) ? w * 512 : w * 1024;

    const int kiter = K >> 5;                   // >= 24 for all our shapes

#define STAGE_T(kk, s)                                                      \
    {   const int k0_ = (kk) * 32;                                          \
        if constexpr (TN == 256) {                                          \
            gload_lds16(Ab + k0_, &As[s][asd]);                             \
            gload_lds16(Bb + k0_,                 &Bs[s][bsd]);             \
            gload_lds16(Bb + (size_t)128 * K + k0_, &Bs[s][4096 + bsd]);    \
        } else {                                                            \
            gload_lds16(Ab + k0_, &As[s][asd]);                             \
            if constexpr (TM == 128) gload_lds16(Ab + 16 * K + k0_, &As[s][asd + 512]); \
            gload_lds16(Bb + k0_,          &Bs[s][bsd]);                    \
            gload_lds16(Bb + 16 * K + k0_, &Bs[s][bsd + 512]);              \
        }                                                                   \
    }

    // prologue: stage tiles 0 and 1 (depth-2 ahead)
    STAGE_T(0, 0);
    STAGE_T(1, 1);

    int cur = 0;
    for (int t = 0; t < kiter; ++t) {
        // wait: tile t's loads complete; tile t+1's (newest LPT) may stay in flight
        if (t + 1 < kiter) {
            if constexpr (TN == 256)      asm volatile("s_waitcnt vmcnt(3)" ::: "memory");
            else if constexpr (TM == 128) asm volatile("s_waitcnt vmcnt(4)" ::: "memory");
            else                          asm volatile("s_waitcnt vmcnt(3)" ::: "memory");
        } else {
            asm volatile("s_waitcnt vmcnt(0)" ::: "memory");
        }
        __builtin_amdgcn_s_barrier();
        __builtin_amdgcn_sched_barrier(0);      // pin: nothing moves across sync point

        const u16* Asc = &As[cur][0];
        const u16* Bsc = &Bs[cur][0];
        bf16x8 af[MT], bf[4];
#pragma unroll
        for (int mt = 0; mt < MT; mt++) af[mt] = ldfrag(&Asc[(wm + mt * 16 + lr) * 32 + lq * 8]);
#pragma unroll
        for (int nt = 0; nt < 4; nt++) bf[nt] = ldfrag(&Bsc[(wn + nt * 16 + lr) * 32 + lq * 8]);
#pragma unroll
        for (int mt = 0; mt < MT; mt++)
#pragma unroll
            for (int nt = 0; nt < 4; nt++)
                acc[mt][nt] = TR ? mfma16(bf[nt], af[mt], acc[mt][nt])
                                 : mfma16(af[mt], bf[nt], acc[mt][nt]);

        if (t + 2 < kiter) {                    // stage t+2 into the buffer freed at t-1
            int nb = cur + 2; if (nb >= 3) nb -= 3;
            STAGE_T(t + 2, nb);
        }
        cur = (cur + 1 == 3) ? 0 : cur + 1;
    }
#undef STAGE_T

    if (EPI == 4) {
        // original orientation: acc[mt][nt][r] = C[row=lq*4+r within mt][col=lr within nt]
        const bool isv = (bn >= 1536);          // TN=256 tiles: 1536 = 6*256, clean split
        u16* vtg = (u16*)aux;             // VtG base (u16), passed via aux
#pragma unroll
        for (int mt = 0; mt < MT; mt++) {
            int row0 = bm + wm + mt * 16 + lq * 4;
            if (!isv) {
#pragma unroll
                for (int r = 0; r < 4; r++) {
                    size_t ro = (size_t)(row0 + r) * QK_LD;
#pragma unroll
                    for (int nt = 0; nt < 4; nt++) {
                        int col = bn + wn + nt * 16 + lr;
                        float v = acc[mt][nt][r] + bias[col];
                        if (col < 768) v *= 0.125f;     // pre-scale Q (exact pow2)
                        ((u16*)outp)[ro + col] = f2b(v);
                    }
                }
            } else {
                int bloc = row0 >> 10;          // batch within this buffer
                int s = row0 & 1023;            // seq position (multiple of 4)
#pragma unroll
                for (int nt = 0; nt < 4; nt++) {
                    int col = bn + wn + nt * 16 + lr;
                    int he = col - 1536;        // h*64 + e
                    float bcol = bias[col];
                    u16x4 pk;
                    pk[0] = f2b(acc[mt][nt][0] + bcol);
                    pk[1] = f2b(acc[mt][nt][1] + bcol);
                    pk[2] = f2b(acc[mt][nt][2] + bcol);
                    pk[3] = f2b(acc[mt][nt][3] + bcol);
                    *(u16x4*)&vtg[(size_t)bloc * (NH * 64 * SEQ)
                                  + (size_t)he * SEQ + s] = pk;
                }
            }
        }
        return;
    }

    // transposed-C epilogue: thread holds row = wm+mt*16+lr,
    // cols = wn+nt*16+lq*4 .. +3  -> fully vectorized stores.
#pragma unroll
    for (int mt = 0; mt < MT; mt++) {
        int row = bm + wm + mt * 16 + lr;
        size_t ro = (size_t)row * N;
#pragma unroll
        for (int nt = 0; nt < 4; nt++) {
            int col0 = bn + wn + nt * 16 + lq * 4;
            f32x4 v = acc[mt][nt] + *(const f32x4*)&bias[col0];
            if (EPI == 0) {
                u16x4 pk;
#pragma unroll
                for (int r = 0; r < 4; r++) pk[r] = f2b(v[r]);
                *(u16x4*)&((u16*)outp)[ro + col0] = pk;
            } else if (EPI == 2) {
                u16x4 pk;
#pragma unroll
                for (int r = 0; r < 4; r++) {
                    float x = v[r];
                    float y = 0.7978845608028654f * (x + 0.044715f * x * x * x);
                    pk[r] = f2b(x / (1.0f + __expf(-2.0f * y)));
                }
                *(u16x4*)&((u16*)outp)[ro + col0] = pk;
            } else {  // EPI 1 / 3: fp32 out = v + aux
                f32x4 a4 = *(const f32x4*)&aux[ro + col0];
                v += a4;
                *(f32x4*)&((float*)outp)[ro + col0] = v;
            }
        }
    }
}

// ---------- flash attention (MFMA): block = (64 q-rows, batch*head) ----------
// R12 version (proven): XCD-chunk swizzle (Path A), exact skip-rescale,
// setprio around MFMA clusters, Q pre-scaled upstream.
__global__ __launch_bounds__(256, 5) void attn_kernel(
    const u16* __restrict__ qk, const u16* __restrict__ vtg,
    u16* __restrict__ z, int b0, int bq0)
{
    __shared__ __align__(16) u16 Ks[64 * 72];
    __shared__ __align__(16) u16 Vt[64 * 72];
    __shared__ __align__(16) u16 Ps[4][16 * 72];

    int qt, bh;
    if (gridDim.y == 96) {                  // Path A: XCD-chunked (bijective)
        int F = (int)(blockIdx.y * gridDim.x + blockIdx.x);  // HW dispatch order
        int xcd = F & 7, idx = F >> 3;      // idx in [0,192)
        bh = xcd * 12 + (idx >> 4);         // 12 panels per XCD
        qt = 15 - (idx & 15);               // heavy-first within panel
    } else {
        qt = (int)(gridDim.x - 1) - (int)blockIdx.x;   // heavy blocks first
        bh = blockIdx.y;
    }
    const int b = b0 + bh / NH, h = bh % NH;
    const int tid = threadIdx.x, w = tid >> 6, l = tid & 63;
    const int lr = l & 15, lq = l >> 4;
    const int qbase = qt * 64;
    const u16* qp = qk + (size_t)(b - bq0) * SEQ * QK_LD + h * 64;
    const u16* kp = qp + 768;
    const u16* vthead = vtg + ((size_t)(b - bq0) * NH + h) * (64 * SEQ);
    u16* PsW = &Ps[w][0];

    // Q fragments in registers (B-operand of swapped QK): row w*16+lr, k-slice lq*8
    bf16x8 aq0, aq1;
    {
        const u16* qrow = qp + (size_t)(qbase + w * 16 + lr) * QK_LD + lq * 8;
        aq0 = ldfrag(qrow);
        aq1 = ldfrag(qrow + 32);
    }

    float m_i = -1e30f;       // running max for q = w*16 + lr (softmax domain)
    float l_i = 0.f;          // running denom for q = w*16 + lr
    f32x4 O[4];
#pragma unroll
    for (int i = 0; i < 4; i++) O[i] = f32x4{0.f, 0.f, 0.f, 0.f};

    const int nkt = qt + 1;                 // causal: tiles 0..qt
    const int srow = tid >> 2;              // 0..63  (K row / V e-row)
    const int spart = (tid & 3) * 16;       // 0,16,32,48

    // prefetch tile 0 into registers (T14: issue-early / write-late)
    u16x8 kreg0, kreg1, vreg0, vreg1;
    {
        const u16* ks = kp + (size_t)srow * QK_LD + spart;
        kreg0 = *(const u16x8*)ks;
        kreg1 = *(const u16x8*)(ks + 8);
        const u16* vs = vthead + (size_t)srow * SEQ + spart;
        vreg0 = *(const u16x8*)vs;
        vreg1 = *(const u16x8*)(vs + 8);
    }

    for (int kt = 0; kt < nkt; ++kt) {
        __syncthreads();                    // prev tile's MFMAs done reading Ks/Vt
        *(u16x8*)&Ks[srow * 72 + spart]     = kreg0;
        *(u16x8*)&Ks[srow * 72 + spart + 8] = kreg1;
        *(u16x8*)&Vt[srow * 72 + spart]     = vreg0;
        *(u16x8*)&Vt[srow * 72 + spart + 8] = vreg1;
        __syncthreads();
        if (kt + 1 < nkt) {                 // issue next-tile loads; latency hides under compute
            const u16* ks = kp + (size_t)((kt + 1) * 64 + srow) * QK_LD + spart;
            kreg0 = *(const u16x8*)ks;
            kreg1 = *(const u16x8*)(ks + 8);
            const u16* vs = vthead + (size_t)srow * SEQ + (kt + 1) * 64 + spart;
            vreg0 = *(const u16x8*)vs;
            vreg1 = *(const u16x8*)(vs + 8);
        }

        // ---- swapped QK^T: S^T[k][q], lane holds q = lr, k = nt*16 + lq*4 + r ----
        f32x4 S[4];
#pragma unroll
        for (int nt = 0; nt < 4; nt++) S[nt] = f32x4{0.f, 0.f, 0.f, 0.f};
        __builtin_amdgcn_s_setprio(1);
#pragma unroll
        for (int nt = 0; nt < 4; nt++) {
            bf16x8 bk0 = ldfrag(&Ks[(nt * 16 + lr) * 72 + lq * 8]);
            bf16x8 bk1 = ldfrag(&Ks[(nt * 16 + lr) * 72 + 32 + lq * 8]);
            S[nt] = mfma16(bk0, aq0, S[nt]);
            S[nt] = mfma16(bk1, aq1, S[nt]);
        }
        __builtin_amdgcn_s_setprio(0);

        // ---- online softmax, lane-local per q-row (mask only on diag tile) ----
        const bool diag = (kt == qt);
        float mx = -1e30f;
#pragma unroll
        for (int nt = 0; nt < 4; nt++)
#pragma unroll
            for (int r = 0; r < 4; r++) {
                float sv = S[nt][r];        // Q pre-scaled upstream
                if (diag) sv = (nt * 16 + lq * 4 + r <= w * 16 + lr) ? sv : -1e30f;
                S[nt][r] = sv;
                mx = fmaxf(mx, sv);
            }
        mx = fmaxf(mx, __shfl_xor(mx, 16));
        mx = fmaxf(mx, __shfl_xor(mx, 32));
        const bool need = __any(mx > m_i);  // wave-uniform; exact skip when false
        float mn = m_i, alpha = 1.f;
        if (need) {
            mn = fmaxf(m_i, mx);
            alpha = __expf(m_i - mn);
            m_i = mn;
        }
        float rs = 0.f;
#pragma unroll
        for (int nt = 0; nt < 4; nt++) {
            u16x4 pk;
#pragma unroll
            for (int r = 0; r < 4; r++) {
                float pe = __expf(S[nt][r] - mn);
                rs += pe;
                pk[r] = f2b(pe);
            }
            // Ps[q = lr][k = nt*16 + lq*4 .. +3], 8B aligned
            *(u16x4*)&PsW[lr * 72 + nt * 16 + lq * 4] = pk;
        }
        rs += __shfl_xor(rs, 16);
        rs += __shfl_xor(rs, 32);
        if (need) {
            l_i = l_i * alpha + rs;
            // ---- rescale O (O-domain: lane holds e = lr, q rows lq*4+r) ----
#pragma unroll
            for (int r = 0; r < 4; r++) {
                float ar = __shfl(alpha, (l & 48) | (lq * 4 + r));
                O[0][r] *= ar; O[1][r] *= ar; O[2][r] *= ar; O[3][r] *= ar;
            }
        } else {
            l_i += rs;
        }

        // ---- PV (Ps is wave-private: no barrier, only lgkmcnt) ----
        __builtin_amdgcn_s_setprio(1);
#pragma unroll
        for (int kq = 0; kq < 2; kq++) {
            bf16x8 ap = ldfrag(&PsW[lr * 72 + kq * 32 + lq * 8]);
#pragma unroll
            for (int ot = 0; ot < 4; ot++) {
                bf16x8 bv = ldfrag(&Vt[(ot * 16 + lr) * 72 + kq * 32 + lq * 8]);
                O[ot] = mfma16(ap, bv, O[ot]);
            }
        }
        __builtin_amdgcn_s_setprio(0);
    }

    // ---- epilogue: bring l_i to O-domain, divide, store ----
    float li[4];
#pragma unroll
    for (int r = 0; r < 4; r++)
        li[r] = __shfl(l_i, (l & 48) | (lq * 4 + r));
#pragma unroll
    for (int ot = 0; ot < 4; ot++)
#pragma unroll
        for (int r = 0; r < 4; r++) {
            int q = qbase + w * 16 + lq * 4 + r;
            size_t t = (size_t)b * SEQ + q;
            z[t * DM + h * 64 + ot * 16 + lr] = f2b(O[ot][r] / li[r]);
        }
}

// ---------- launch ----------
extern "C" void kernel_launch(void* const* d_in, const int* in_sizes, int n_in,
                              void* d_out, int out_size, void* d_ws, size_t ws_size,
                              hipStream_t stream) {
    const float* resid_pre = (const float*)d_in[0];
    const float* W_Q  = (const float*)d_in[1];
    const float* b_Q  = (const float*)d_in[2];
    const float* W_K  = (const float*)d_in[3];
    const float* b_K  = (const float*)d_in[4];
    const float* W_V  = (const float*)d_in[5];
    const float* b_V  = (const float*)d_in[6];
    const float* W_O  = (const float*)d_in[7];
    const float* b_O  = (const float*)d_in[8];
    const float* ln1w = (const float*)d_in[9];
    const float* ln1b = (const float*)d_in[10];
    const float* ln2w = (const float*)d_in[11];
    const float* ln2b = (const float*)d_in[12];
    const float* W_in  = (const float*)d_in[13];
    const float* b_in  = (const float*)d_in[14];
    const float* W_out = (const float*)d_in[15];
    const float* b_out = (const float*)d_in[16];

    u16* ws16       = (u16*)d_ws;
    u16* Wqkv_t     = ws16 + OFF_WQKV;
    u16* Wo_t       = ws16 + OFF_WO;
    u16* Win_t      = ws16 + OFF_WIN;
    u16* Wout_t     = ws16 + OFF_WOUT;
    float* bias_qkv = (float*)(ws16 + OFF_BQKV);
    float* outp  = (float*)d_out;    // fp32 output (reference dtype)
    float* resid = (float*)d_out;    // resid_mid lives in d_out until final add

    if (ws_size >= PATHA_BYTES) {
        // ---- Path A (77 MB ws) ----
        u16* nbuf    = ws16 + A_NBUF;
        u16* qkbuf   = ws16 + A_QKV;                          // [8192][1536] bf16
        u16* vtgA    = ws16 + A_QKV + (size_t)T_TOK * QK_LD;  // [8][12][64][1024] bf16
        u16* zbuf    = ws16 + A_Z;
        u16* n2buf   = ws16 + A_N2;
        u16* postbuf = ws16 + A_POST;

        prep_kernel<<<TT_WOUT + 1 + T_TOK, 256, 0, stream>>>(
            W_Q, W_K, W_V, W_O, W_in, W_out, b_Q, b_K, b_V,
            Wqkv_t, Wo_t, Win_t, Wout_t, bias_qkv,
            resid_pre, ln1w, ln1b, nbuf);
        gemm_bt_kernel<4, 128, 256><<<dim3(T_TOK / 128, QKV_LD / 256), 512, 0, stream>>>(
            nbuf, Wqkv_t, bias_qkv, (const float*)vtgA, qkbuf, QKV_LD, DM);
        attn_kernel<<<dim3(SEQ / 64, 8 * NH), 256, 0, stream>>>(qkbuf, vtgA, zbuf, 0, 0);
        gemm_bt_kernel<1, 64, 128><<<dim3(T_TOK / 64, DM / 128), 256, 0, stream>>>(
            zbuf, Wo_t, b_O, resid_pre, resid, DM, DM);
        ln_kernel<<<T_TOK, 256, 0, stream>>>(resid, ln2w, ln2b, n2buf);
        gemm_bt_kernel<2, 128, 256><<<dim3(T_TOK / 128, DMLP / 256), 512, 0, stream>>>(
            n2buf, Win_t, b_in, nullptr, postbuf, DMLP, DM);
        gemm_bt_kernel<3, 64, 128><<<dim3(T_TOK / 64, DM / 128), 256, 0, stream>>>(
            postbuf, Wout_t, b_out, resid, outp, DM, DMLP);
    } else {
        // ---- Path B (44 MB ws): per-batch attention, chunked MLP ----
        u16* zbuf   = ws16 + B_Z;
        u16* qkb    = ws16 + B_QKVB;                          // [1024][1536] bf16
        u16* vtgB   = qkb + (size_t)SEQ * QK_LD;              // [12][64][1024] bf16
        u16* nbuf   = ws16 + B_NBUF;
        u16* n2buf  = ws16 + B_N2;
        u16* postc  = ws16 + B_POSTC;

        prep_kernel<<<TT_WOUT + 1 + T_TOK, 256, 0, stream>>>(
            W_Q, W_K, W_V, W_O, W_in, W_out, b_Q, b_K, b_V,
            Wqkv_t, Wo_t, Win_t, Wout_t, bias_qkv,
            resid_pre, ln1w, ln1b, nbuf);
        for (int b = 0; b < 8; b++) {
            gemm_bt_kernel<4, 128, 256><<<dim3(SEQ / 128, QKV_LD / 256), 512, 0, stream>>>(
                nbuf + (size_t)b * SEQ * DM, Wqkv_t, bias_qkv, (const float*)vtgB, qkb, QKV_LD, DM);
            attn_kernel<<<dim3(SEQ / 64, NH), 256, 0, stream>>>(qkb, vtgB, zbuf, b, b);
        }
        gemm_bt_kernel<1, 64, 128><<<dim3(T_TOK / 64, DM / 128), 256, 0, stream>>>(
            zbuf, Wo_t, b_O, resid_pre, resid, DM, DM);
        ln_kernel<<<T_TOK, 256, 0, stream>>>(resid, ln2w, ln2b, n2buf);
        for (int c = 0; c < 4; c++) {
            const size_t r0 = (size_t)c * 2048;
            gemm_bt_kernel<2, 128, 256><<<dim3(2048 / 128, DMLP / 256), 512, 0, stream>>>(
                n2buf + r0 * DM, Win_t, b_in, nullptr, postc, DMLP, DM);
            gemm_bt_kernel<3, 64, 128><<<dim3(2048 / 64, DM / 128), 256, 0, stream>>>(
                postc, Wout_t, b_out, resid + r0 * DM, outp + r0 * DM, DM, DMLP);
        }
    }
}